// Round 9
// baseline (343.091 us; speedup 1.0000x reference)
//
#include <hip/hip_runtime.h>

#define Hh   256
#define NCn  20000
#define N1n  60000
#define N2n  60000
#define En   200000
#define Bn   512
#define OUTn 128
#define KA   96        // layer-0 packed-A stride / GEMM K
#define PGW  1792      // per-graph concat width (7 x 256)

using bf16x8 = __attribute__((ext_vector_type(8))) __bf16;
using f32x4  = __attribute__((ext_vector_type(4))) float;
using f32x2  = __attribute__((ext_vector_type(2))) float;

__device__ __forceinline__ float bf2f(unsigned short u) {
    union { unsigned int i; float f; } v; v.i = ((unsigned int)u) << 16; return v.f;
}
__device__ __forceinline__ unsigned short f2bf(float f) {
    union { float f; unsigned int i; } v; v.f = f;
    unsigned int r = v.i + 0x7FFFu + ((v.i >> 16) & 1u);
    return (unsigned short)(r >> 16);
}
__device__ __forceinline__ int imax(int a, int b) { return a > b ? a : b; }

// ---- fp8 e4m3 pack/unpack (hardware cvt on gfx950; guarded manual fallback) -----------
#if __has_builtin(__builtin_amdgcn_cvt_pk_fp8_f32) && __has_builtin(__builtin_amdgcn_cvt_pk_f32_fp8)
__device__ __forceinline__ unsigned int pack4_fp8(float v0, float v1, float v2, float v3) {
    int r = __builtin_amdgcn_cvt_pk_fp8_f32(v0, v1, 0, false);
    r = __builtin_amdgcn_cvt_pk_fp8_f32(v2, v3, r, true);
    return (unsigned int)r;
}
__device__ __forceinline__ void unpack4_fp8(unsigned int u, float& v0, float& v1, float& v2, float& v3) {
    f32x2 lo = __builtin_amdgcn_cvt_pk_f32_fp8((int)u, false);
    f32x2 hi = __builtin_amdgcn_cvt_pk_f32_fp8((int)u, true);
    v0 = lo[0]; v1 = lo[1]; v2 = hi[0]; v3 = hi[1];
}
#else
__device__ __forceinline__ unsigned char f32_to_fp8_1(float f) {
    union { float f; unsigned int i; } v; v.f = f;
    unsigned int s = (v.i >> 24) & 0x80u;
    float af = fabsf(f);
    if (!(af > 0.f)) return (unsigned char)s;
    if (af > 448.f) af = 448.f;
    v.f = af;
    int e = (int)((v.i >> 23) & 0xff) - 127;
    unsigned int m = v.i & 0x7fffffu;
    if (e < -9) return (unsigned char)s;
    if (e < -6) {
        int rb = 21 + (-6 - e) - 1;
        unsigned int man = 0x800000u | m;
        unsigned int keep = man >> (rb + 1);
        unsigned int rem = man & ((1u << (rb + 1)) - 1);
        unsigned int half = 1u << rb;
        keep += (rem > half) || (rem == half && (keep & 1));
        return (unsigned char)(s | keep);
    }
    unsigned int keep = m >> 20;
    unsigned int rem = m & 0xfffffu;
    keep += (rem > 0x80000u) || (rem == 0x80000u && (keep & 1));
    unsigned int ee = (unsigned int)(e + 7);
    if (keep == 8) { keep = 0; ee += 1; }
    if (ee >= 16) { ee = 15; keep = 6; }
    return (unsigned char)(s | (ee << 3) | keep);
}
__device__ __forceinline__ unsigned int pack4_fp8(float v0, float v1, float v2, float v3) {
    return (unsigned int)f32_to_fp8_1(v0) | ((unsigned int)f32_to_fp8_1(v1) << 8) |
           ((unsigned int)f32_to_fp8_1(v2) << 16) | ((unsigned int)f32_to_fp8_1(v3) << 24);
}
__device__ __forceinline__ float fp8_to_f32_1(unsigned int b) {
    unsigned int s = b >> 7, e = (b >> 3) & 15u, m = b & 7u;
    float v;
    if (e == 0) v = (float)m * (1.0f / 512.0f);
    else { union { unsigned int i; float f; } u; u.i = ((e + 120u) << 23) | (m << 20); v = u.f; }
    return s ? -v : v;
}
__device__ __forceinline__ void unpack4_fp8(unsigned int u, float& v0, float& v1, float& v2, float& v3) {
    v0 = fp8_to_f32_1(u & 0xffu); v1 = fp8_to_f32_1((u >> 8) & 0xffu);
    v2 = fp8_to_f32_1((u >> 16) & 0xffu); v3 = fp8_to_f32_1((u >> 24) & 0xffu);
}
#endif

struct CPtr4 { const int* p[4]; };
struct IPtr4 { int* p[4]; };
struct UPtr4 { uint2* p[4]; };

// ---------------- fused prep: pack A panels + compact gather tables + zero + bounds ----
// ranges: [0,c0) A0/A0c; [c0,c1) A1/xr1c; [c1,c2) A2/xr2c; [c2,c3) zero deg_fill; [c3,c4) bounds
__global__ void prep_all(const float* __restrict__ xc, const float* __restrict__ x1,
                         const float* __restrict__ x2,
                         unsigned short* __restrict__ A0, unsigned short* __restrict__ A1,
                         unsigned short* __restrict__ A2, unsigned short* __restrict__ A0c,
                         unsigned short* __restrict__ xr1c, unsigned short* __restrict__ xr2c,
                         int* __restrict__ deg_fill,
                         const int* __restrict__ bc, const int* __restrict__ b1,
                         const int* __restrict__ b2, int* __restrict__ bound) {
    const int c0 = NCn * 16, c1 = c0 + N1n * 8, c2 = c1 + N2n * 8;
    const int c3 = c2 + 320000, c4 = c3 + 3 * (Bn + 1);
    int idx = blockIdx.x * 256 + threadIdx.x;
    if (idx < c0) {
        int m = idx >> 4, c = (idx & 15) * 4;
        float4 v = *reinterpret_cast<const float4*>(xc + (size_t)m * 64 + c);
        ushort4 o = { f2bf(v.x), f2bf(v.y), f2bf(v.z), f2bf(v.w) };
        *reinterpret_cast<ushort4*>(A0 + (size_t)m * KA + c) = o;
        *reinterpret_cast<ushort4*>(A0c + (size_t)m * 64 + c) = o;
    } else if (idx < c2) {
        bool is1 = idx < c1;
        int i = idx - (is1 ? c0 : c1);
        int m = i >> 3, c = (i & 7) * 4;
        const float* x = is1 ? x1 : x2;
        unsigned short* A = is1 ? A1 : A2;
        unsigned short* xr = is1 ? xr1c : xr2c;
        ushort4 o = { 0, 0, 0, 0 };
        if (c < 16) {
            float4 v = *reinterpret_cast<const float4*>(x + (size_t)m * 16 + c);
            o.x = f2bf(v.x); o.y = f2bf(v.y); o.z = f2bf(v.z); o.w = f2bf(v.w);
            *reinterpret_cast<ushort4*>(xr + (size_t)m * 16 + c) = o;
        }
        *reinterpret_cast<ushort4*>(A + (size_t)m * KA + 64 + c) = o;
    } else if (idx < c3) {
        deg_fill[idx - c2] = 0;
    } else if (idx < c4) {
        int i4 = idx - c3;
        int t = i4 / (Bn + 1); int b = i4 - t * (Bn + 1);
        const int* batch = (t == 0) ? bc : (t == 1) ? b1 : b2;
        int n = (t == 0) ? NCn : (t == 1) ? N1n : N2n;
        int lo = 0, hi = n;
        while (lo < hi) { int mid = (lo + hi) >> 1; if (batch[mid] < b) lo = mid + 1; else hi = mid; }
        bound[i4] = lo;
    }
}

// ---------------- CSR build (relation-batched, dst side only) --------------------------
__device__ __forceinline__ int degoff_of(int rel) {
    const int t[4] = { 0, N1n, N1n + NCn, N1n + NCn + N2n };
    return t[rel];
}
__device__ __forceinline__ int nrel_of(int rel) {
    const int t[4] = { N1n, NCn, N2n, NCn };
    return t[rel];
}
__device__ __forceinline__ void rel_chunk(int b, int& rel, int& c) {
    if (b < 59)       { rel = 0; c = b; }
    else if (b < 79)  { rel = 1; c = b - 59; }
    else if (b < 138) { rel = 2; c = b - 79; }
    else              { rel = 3; c = b - 138; }
}
__global__ void deg_count_all(CPtr4 dst, int* __restrict__ deg_all) {
    int i = blockIdx.x * 256 + threadIdx.x;
    if (i >= 4 * En) return;
    int rel = i / En; int e = i - rel * En;
    atomicAdd(&deg_all[degoff_of(rel) + dst.p[rel][e]], 1);
}
__global__ void __launch_bounds__(1024) scan_chunk_all(const int* __restrict__ deg_all,
                                                       IPtr4 rp, int* __restrict__ partials) {
    int rel, c; rel_chunk(blockIdx.x, rel, c);
    int n = nrel_of(rel);
    __shared__ int sh[1024];
    int tid = threadIdx.x;
    int i = c * 1024 + tid;
    int v = (i < n) ? deg_all[degoff_of(rel) + i] : 0;
    sh[tid] = v; __syncthreads();
    for (int off = 1; off < 1024; off <<= 1) {
        int t = (tid >= off) ? sh[tid - off] : 0; __syncthreads();
        sh[tid] += t; __syncthreads();
    }
    if (i < n) rp.p[rel][i] = sh[tid] - v;
    if (tid == 1023) partials[rel * 64 + c] = sh[1023];
}
__global__ void scan_partials_all(int* partials) {
    const int nch[4] = { 59, 20, 59, 20 };
    int rel = blockIdx.x;
    __shared__ int sh[64];
    int tid = threadIdx.x;
    int v = (tid < nch[rel]) ? partials[rel * 64 + tid] : 0;
    sh[tid] = v; __syncthreads();
    for (int off = 1; off < 64; off <<= 1) {
        int t = (tid >= off) ? sh[tid - off] : 0; __syncthreads();
        sh[tid] += t; __syncthreads();
    }
    if (tid < nch[rel]) partials[rel * 64 + tid] = sh[tid] - v;
}
__global__ void __launch_bounds__(1024) scan_add_all(IPtr4 rp, const int* __restrict__ partials) {
    int rel, c; rel_chunk(blockIdx.x, rel, c);
    int n = nrel_of(rel);
    int tid = threadIdx.x;
    int i = c * 1024 + tid;
    if (i < n) rp.p[rel][i] += partials[rel * 64 + c];
    if (c == 0 && tid == 0) rp.p[rel][n] = En;
}
// scatter: pay[pos] = { src, 1/deg(dst) } in dst-CSR order
__global__ void scatter_all(CPtr4 src, CPtr4 dst, CPtr4 rp, int* fill_all, UPtr4 pay) {
    int i = blockIdx.x * 256 + threadIdx.x;
    if (i >= 4 * En) return;
    int rel = i / En; int e = i - rel * En;
    int d = dst.p[rel][e];
    int rb = rp.p[rel][d];
    int deg = rp.p[rel][d + 1] - rb;
    float w = 1.0f / (float)imax(deg, 1);
    int pos = rb + atomicAdd(&fill_all[degoff_of(rel) + d], 1);
    pay.p[rel][pos] = make_uint2((unsigned int)src.p[rel][e], __float_as_uint(w));
}

// ---------------- raw-feature segment mean (layer 0), compact L2-resident sources ------
struct RawDesc {
    const unsigned short* feat;   // compact table
    const int* rowptr;
    const uint2* pay;             // .x = src
    unsigned short* out;          // stride 96
    int fstride;                  // 16 or 64
    int sh;                       // log2(col-groups of 4)
    int n_dst;
    int ocol;
};
__global__ void raw_agg(RawDesc d0, RawDesc d1, RawDesc d2, RawDesc d3) {
    RawDesc d = (blockIdx.y == 0) ? d0 : (blockIdx.y == 1) ? d1 : (blockIdx.y == 2) ? d2 : d3;
    int idx = blockIdx.x * 256 + threadIdx.x;
    int node = idx >> d.sh;
    int c4 = idx & ((1 << d.sh) - 1);
    if (node >= d.n_dst) return;
    int s = d.rowptr[node], e = d.rowptr[node + 1];
    float a0 = 0.f, a1 = 0.f, a2 = 0.f, a3 = 0.f;
    float b0 = 0.f, b1 = 0.f, b2 = 0.f, b3 = 0.f;
    int i = s;
    for (; i + 1 < e; i += 2) {
        int sc1 = (int)d.pay[i].x, sc2 = (int)d.pay[i + 1].x;
        ushort4 v1 = *reinterpret_cast<const ushort4*>(d.feat + (size_t)sc1 * d.fstride + c4 * 4);
        ushort4 v2 = *reinterpret_cast<const ushort4*>(d.feat + (size_t)sc2 * d.fstride + c4 * 4);
        a0 += bf2f(v1.x); a1 += bf2f(v1.y); a2 += bf2f(v1.z); a3 += bf2f(v1.w);
        b0 += bf2f(v2.x); b1 += bf2f(v2.y); b2 += bf2f(v2.z); b3 += bf2f(v2.w);
    }
    if (i < e) {
        int sc1 = (int)d.pay[i].x;
        ushort4 v1 = *reinterpret_cast<const ushort4*>(d.feat + (size_t)sc1 * d.fstride + c4 * 4);
        a0 += bf2f(v1.x); a1 += bf2f(v1.y); a2 += bf2f(v1.z); a3 += bf2f(v1.w);
    }
    a0 += b0; a1 += b1; a2 += b2; a3 += b3;
    float inv = 1.0f / (float)imax(e - s, 1);
    ushort4 o;
    o.x = f2bf(a0 * inv); o.y = f2bf(a1 * inv); o.z = f2bf(a2 * inv); o.w = f2bf(a3 * inv);
    *reinterpret_cast<ushort4*>(d.out + (size_t)node * KA + d.ocol + c4 * 4) = o;
}

// ---------------- layer-0 weight folding ------------------------------------------------
__global__ void wfold(const float* __restrict__ Wm, const float* __restrict__ Wr,
                      const float* __restrict__ Wpc, const float* __restrict__ Wp1,
                      const float* __restrict__ Wp2, unsigned short* __restrict__ Wt3) {
    __shared__ float cA[256], cB[256], cC[256];
    int n = blockIdx.x, mat = blockIdx.y, tid = threadIdx.x;
    for (int j = tid; j < 256; j += 128) {
        if (mat == 0) {
            cA[j] = 0.5f * (Wr[1 * 65536 + j * 256 + n] + Wr[3 * 65536 + j * 256 + n]);
            cB[j] = 0.5f * Wm[1 * 65536 + j * 256 + n];
            cC[j] = 0.5f * Wm[3 * 65536 + j * 256 + n];
        } else if (mat == 1) {
            cA[j] = Wm[0 * 65536 + j * 256 + n];
            cB[j] = Wr[0 * 65536 + j * 256 + n];
            cC[j] = 0.f;
        } else {
            cA[j] = Wm[2 * 65536 + j * 256 + n];
            cB[j] = Wr[2 * 65536 + j * 256 + n];
            cC[j] = 0.f;
        }
    }
    __syncthreads();
    int k = tid;
    if (k >= KA) return;
    float w = 0.f;
    if (k < 64) {
        for (int j = 0; j < 256; ++j) w = fmaf(Wpc[k * 256 + j], cA[j], w);
    } else if (k < 80) {
        const float* Wp = (mat == 2) ? Wp2 : Wp1;
        for (int j = 0; j < 256; ++j) w = fmaf(Wp[(k - 64) * 256 + j], cB[j], w);
    } else if (mat == 0) {
        for (int j = 0; j < 256; ++j) w = fmaf(Wp2[(k - 80) * 256 + j], cC[j], w);
    }
    Wt3[(size_t)mat * 256 * KA + n * KA + k] = f2bf(w);
}

// fused: WPGt + bPG + layer-0 folded biases (bC/bB1/bB2)
__global__ void wprep2(const float* __restrict__ Wm1, const float* __restrict__ Wr1,
                       const float* __restrict__ bm1,
                       const float* __restrict__ Wm0, const float* __restrict__ Wr0,
                       const float* __restrict__ bm0, const float* __restrict__ bpc,
                       const float* __restrict__ bp1, const float* __restrict__ bp2,
                       unsigned short* __restrict__ WPGt, float* __restrict__ bPG,
                       float* __restrict__ bC, float* __restrict__ bB1, float* __restrict__ bB2) {
    int idx = blockIdx.x * 256 + threadIdx.x;
    const float third = 1.0f / 3.0f;
    if (idx < 256 * PGW) {
        int n = idx / PGW, k = idx - n * PGW;
        int blk = k >> 8, kk = k & 255;
        float v;
        switch (blk) {
            case 0:  v = 0.5f * Wm1[1 * 65536 + kk * 256 + n]; break;
            case 1:  v = 0.5f * Wm1[3 * 65536 + kk * 256 + n]; break;
            case 2:  v = 0.5f * (Wr1[1 * 65536 + kk * 256 + n] + Wr1[3 * 65536 + kk * 256 + n]); break;
            case 3:  v = Wm1[0 * 65536 + kk * 256 + n]; break;
            case 4:  v = Wr1[0 * 65536 + kk * 256 + n]; break;
            case 5:  v = Wm1[2 * 65536 + kk * 256 + n]; break;
            default: v = Wr1[2 * 65536 + kk * 256 + n]; break;
        }
        WPGt[idx] = f2bf(v * third);
    } else if (idx < 256 * PGW + 256) {
        int n = idx - 256 * PGW;
        bPG[n] = third * (0.5f * (bm1[1 * 256 + n] + bm1[3 * 256 + n]) + bm1[0 * 256 + n] + bm1[2 * 256 + n]);
    } else if (idx < 256 * PGW + 512) {
        int n = idx - (256 * PGW + 256);
        float s0 = 0, s1 = 0, s2 = 0, t0 = 0, t1 = 0, u0 = 0, u1 = 0;
        for (int j = 0; j < 256; ++j) {
            float wr1 = Wr0[1 * 65536 + j * 256 + n], wr3 = Wr0[3 * 65536 + j * 256 + n];
            float wm1 = Wm0[1 * 65536 + j * 256 + n], wm3 = Wm0[3 * 65536 + j * 256 + n];
            float wm0 = Wm0[0 * 65536 + j * 256 + n], wr0 = Wr0[0 * 65536 + j * 256 + n];
            float wm2 = Wm0[2 * 65536 + j * 256 + n], wr2 = Wr0[2 * 65536 + j * 256 + n];
            float bc = bpc[j], b1 = bp1[j], b2 = bp2[j];
            s0 = fmaf(bc, 0.5f * (wr1 + wr3), s0);
            s1 = fmaf(b1, 0.5f * wm1, s1);
            s2 = fmaf(b2, 0.5f * wm3, s2);
            t0 = fmaf(bc, wm0, t0); t1 = fmaf(b1, wr0, t1);
            u0 = fmaf(bc, wm2, u0); u1 = fmaf(b2, wr2, u1);
        }
        bC[n]  = s0 + s1 + s2 + 0.5f * (bm0[1 * 256 + n] + bm0[3 * 256 + n]);
        bB1[n] = t0 + t1 + bm0[0 * 256 + n];
        bB2[n] = u0 + u1 + bm0[2 * 256 + n];
    }
}

// ---------------- layer-0 GEMM: K=96, N=256, bias+relu, fp8 output ---------------------
struct G96 {
    const unsigned short* A;
    const unsigned short* Wt;
    const float* bias;
    unsigned char* C;          // fp8 e4m3, stride 256 B
    int M;
};
__global__ void __launch_bounds__(256) gemm96(G96 g0, G96 g1, G96 g2) {
    G96 g = (blockIdx.y == 0) ? g0 : (blockIdx.y == 1) ? g1 : g2;
    const int m0 = blockIdx.x * 32;
    if (m0 >= g.M) return;
    const int tid = threadIdx.x;
    const int wid = tid >> 6, lane = tid & 63;
    const int llo = lane & 15, lhi = lane >> 4;
    const int cb = wid * 64;

    const unsigned short* pA[2];
#pragma unroll
    for (int rt = 0; rt < 2; ++rt)
        pA[rt] = g.A + (size_t)(m0 + rt * 16 + llo) * KA + lhi * 8;
    const unsigned short* pB[4];
#pragma unroll
    for (int ct = 0; ct < 4; ++ct)
        pB[ct] = g.Wt + (size_t)(cb + ct * 16 + llo) * KA + lhi * 8;

    f32x4 acc[2][4] = {};
    bf16x8 a0[2], a1[2], a2[2], b0[4], b1[4], b2[4];
#pragma unroll
    for (int t = 0; t < 2; ++t) {
        a0[t] = *reinterpret_cast<const bf16x8*>(pA[t]);
        a1[t] = *reinterpret_cast<const bf16x8*>(pA[t] + 32);
        a2[t] = *reinterpret_cast<const bf16x8*>(pA[t] + 64);
    }
#pragma unroll
    for (int t = 0; t < 4; ++t) {
        b0[t] = *reinterpret_cast<const bf16x8*>(pB[t]);
        b1[t] = *reinterpret_cast<const bf16x8*>(pB[t] + 32);
        b2[t] = *reinterpret_cast<const bf16x8*>(pB[t] + 64);
    }
#pragma unroll
    for (int rt = 0; rt < 2; ++rt)
#pragma unroll
        for (int ct = 0; ct < 4; ++ct) {
            acc[rt][ct] = __builtin_amdgcn_mfma_f32_16x16x32_bf16(b0[ct], a0[rt], acc[rt][ct], 0, 0, 0);
            acc[rt][ct] = __builtin_amdgcn_mfma_f32_16x16x32_bf16(b1[ct], a1[rt], acc[rt][ct], 0, 0, 0);
            acc[rt][ct] = __builtin_amdgcn_mfma_f32_16x16x32_bf16(b2[ct], a2[rt], acc[rt][ct], 0, 0, 0);
        }

#pragma unroll
    for (int rt = 0; rt < 2; ++rt) {
        const int row = m0 + rt * 16 + llo;
#pragma unroll
        for (int ct = 0; ct < 4; ++ct) {
            const int col0 = cb + ct * 16 + lhi * 4;
            float4 bv = *reinterpret_cast<const float4*>(g.bias + col0);
            float v0 = fmaxf(acc[rt][ct][0] + bv.x, 0.f);
            float v1 = fmaxf(acc[rt][ct][1] + bv.y, 0.f);
            float v2 = fmaxf(acc[rt][ct][2] + bv.z, 0.f);
            float v3 = fmaxf(acc[rt][ct][3] + bv.w, 0.f);
            unsigned int o = pack4_fp8(v0, v1, v2, v3);
            *reinterpret_cast<unsigned int*>(g.C + (size_t)row * 256 + col0) = o;
        }
    }
}

// ---------------- per-graph aggregation: 7 descs x 4 range-quarters, 4-way edge ILP ----
struct PDesc {
    const unsigned char* feat;    // [*][256] fp8
    const int* bound;             // 513 entries (per dst node type)
    const int* rowptr;            // nullptr => plain mean over nodes
    const uint2* pay;             // {src, 1/deg} per edge in CSR order
};
struct PAll { PDesc d[7]; };
// part[(desc*4+z)*512*256 + g*256 + col] (f32)
__global__ void __launch_bounds__(256) pg_all(PAll all, float* __restrict__ part) {
    PDesc d = all.d[blockIdx.y];
    const int g = blockIdx.x, z = blockIdx.z;
    const int tid = threadIdx.x, wid = tid >> 6, lane = tid & 63;
    const int ns = d.bound[g], ne = d.bound[g + 1];
    float r0 = 0.f, r1 = 0.f, r2 = 0.f, r3 = 0.f;
    if (d.rowptr) {
        const int es = d.rowptr[ns], ee = d.rowptr[ne];
        const int len = ee - es;
        const int s = es + ((len * z) >> 2), e = es + ((len * (z + 1)) >> 2);
        float a[4][4] = {};
        for (int i = s + wid * 4; i < e; i += 16) {
#pragma unroll
            for (int j = 0; j < 4; ++j) {
                int ij = i + j;
                bool ok = ij < e;
                int idx = ok ? ij : (e - 1);
                uint2 p = d.pay[idx];
                float w = ok ? __uint_as_float(p.y) : 0.f;
                unsigned int u = *reinterpret_cast<const unsigned int*>(
                    d.feat + (size_t)p.x * 256 + lane * 4);
                float f0, f1, f2, f3;
                unpack4_fp8(u, f0, f1, f2, f3);
                a[j][0] = fmaf(f0, w, a[j][0]);
                a[j][1] = fmaf(f1, w, a[j][1]);
                a[j][2] = fmaf(f2, w, a[j][2]);
                a[j][3] = fmaf(f3, w, a[j][3]);
            }
        }
        r0 = (a[0][0] + a[1][0]) + (a[2][0] + a[3][0]);
        r1 = (a[0][1] + a[1][1]) + (a[2][1] + a[3][1]);
        r2 = (a[0][2] + a[1][2]) + (a[2][2] + a[3][2]);
        r3 = (a[0][3] + a[1][3]) + (a[2][3] + a[3][3]);
    } else {
        const int len = ne - ns;
        const int s = ns + ((len * z) >> 2), e = ns + ((len * (z + 1)) >> 2);
        float c0 = 0.f, c1 = 0.f, c2 = 0.f, c3 = 0.f;
        for (int n = s + wid * 2; n < e; n += 8) {
            unsigned int u1 = *reinterpret_cast<const unsigned int*>(
                d.feat + (size_t)n * 256 + lane * 4);
            int n2 = n + 1;
            if (n2 < e) {
                unsigned int u2 = *reinterpret_cast<const unsigned int*>(
                    d.feat + (size_t)n2 * 256 + lane * 4);
                float f0, f1, f2, f3;
                unpack4_fp8(u2, f0, f1, f2, f3);
                c0 += f0; c1 += f1; c2 += f2; c3 += f3;
            }
            float f0, f1, f2, f3;
            unpack4_fp8(u1, f0, f1, f2, f3);
            r0 += f0; r1 += f1; r2 += f2; r3 += f3;
        }
        r0 += c0; r1 += c1; r2 += c2; r3 += c3;
    }
    __shared__ float sh[4][256];
    sh[wid][lane * 4 + 0] = r0; sh[wid][lane * 4 + 1] = r1;
    sh[wid][lane * 4 + 2] = r2; sh[wid][lane * 4 + 3] = r3;
    __syncthreads();
    float r = (sh[0][tid] + sh[1][tid]) + (sh[2][tid] + sh[3][tid]);
    part[(size_t)((blockIdx.y * 4 + z) * Bn + g) * 256 + tid] = r;
}

// combine 4 quarters, normalize by per-graph node count, write bf16 PG
__global__ void __launch_bounds__(256) pg_combine(const float* __restrict__ part,
                                                  const int* __restrict__ bounds,
                                                  unsigned short* __restrict__ PG) {
    const int otab[7] = { 0, 256, 512, 768, 1024, 1280, 1536 };
    const int btab[7] = { 0, 0, 0, 1, 1, 2, 2 };
    int g = blockIdx.x, dsc = blockIdx.y, tid = threadIdx.x;
    const int* b = bounds + btab[dsc] * (Bn + 1);
    int cnt = b[g + 1] - b[g];
    float s = 0.f;
#pragma unroll
    for (int z = 0; z < 4; ++z)
        s += part[(size_t)((dsc * 4 + z) * Bn + g) * 256 + tid];
    s *= 1.0f / (float)imax(cnt, 1);
    PG[(size_t)g * PGW + otab[dsc] + tid] = f2bf(s);
}

// ---------------- final: emb = PG @ WPGt + bPG (MFMA); out = emb @ Wg + bg -------------
__global__ void __launch_bounds__(256) gemm_emb(const unsigned short* __restrict__ PG,
                                                const unsigned short* __restrict__ WPGt,
                                                const float* __restrict__ bPG,
                                                float* __restrict__ emb) {
    constexpr int KSTEPS = PGW / 32;
    const int m0 = blockIdx.x * 32;
    const int tid = threadIdx.x;
    const int wid = tid >> 6, lane = tid & 63;
    const int llo = lane & 15, lhi = lane >> 4;
    const int cb = wid * 64;

    const unsigned short* pA[2];
#pragma unroll
    for (int rt = 0; rt < 2; ++rt)
        pA[rt] = PG + (size_t)(m0 + rt * 16 + llo) * PGW + lhi * 8;
    const unsigned short* pB[4];
#pragma unroll
    for (int ct = 0; ct < 4; ++ct)
        pB[ct] = WPGt + (size_t)(cb + ct * 16 + llo) * PGW + lhi * 8;

    f32x4 acc[2][4] = {};
    bf16x8 aX[2], bX[4], aY[2], bY[4];
    auto LD = [&](bf16x8 (&a)[2], bf16x8 (&b)[4], int ks) {
        if (ks < KSTEPS) {
            const int ko = ks * 32;
#pragma unroll
            for (int t = 0; t < 2; ++t) a[t] = *reinterpret_cast<const bf16x8*>(pA[t] + ko);
#pragma unroll
            for (int t = 0; t < 4; ++t) b[t] = *reinterpret_cast<const bf16x8*>(pB[t] + ko);
        }
    };
    auto FM = [&](bf16x8 (&a)[2], bf16x8 (&b)[4]) {
#pragma unroll
        for (int rt = 0; rt < 2; ++rt)
#pragma unroll
            for (int ct = 0; ct < 4; ++ct)
                acc[rt][ct] = __builtin_amdgcn_mfma_f32_16x16x32_bf16(b[ct], a[rt], acc[rt][ct], 0, 0, 0);
    };
    LD(aX, bX, 0);
    for (int ks = 0; ks < KSTEPS; ks += 2) {
        LD(aY, bY, ks + 1);
        FM(aX, bX);
        LD(aX, bX, ks + 2);
        FM(aY, bY);
    }

#pragma unroll
    for (int rt = 0; rt < 2; ++rt) {
        const int row = m0 + rt * 16 + llo;
#pragma unroll
        for (int ct = 0; ct < 4; ++ct) {
            const int col0 = cb + ct * 16 + lhi * 4;
            float4 bv = *reinterpret_cast<const float4*>(bPG + col0);
            float4 o;
            o.x = acc[rt][ct][0] + bv.x; o.y = acc[rt][ct][1] + bv.y;
            o.z = acc[rt][ct][2] + bv.z; o.w = acc[rt][ct][3] + bv.w;
            *reinterpret_cast<float4*>(emb + (size_t)row * Hh + col0) = o;
        }
    }
}

__global__ void __launch_bounds__(128) out_final(const float* __restrict__ emb,
                                                 const float* __restrict__ Wg,
                                                 const float* __restrict__ bg,
                                                 float* __restrict__ out) {
    __shared__ float es_[256];
    int g = blockIdx.x, o = threadIdx.x;
    es_[o] = emb[(size_t)g * Hh + o];
    es_[o + 128] = emb[(size_t)g * Hh + 128 + o];
    __syncthreads();
    float acc = bg[o];
#pragma unroll 8
    for (int k = 0; k < 256; ++k) acc = fmaf(es_[k], Wg[k * OUTn + o], acc);
    out[(size_t)g * OUTn + o] = acc;
}

// ---------------- host orchestration ----------------------------------------------------
extern "C" void kernel_launch(void* const* d_in, const int* in_sizes, int n_in,
                              void* d_out, int out_size, void* d_ws, size_t ws_size,
                              hipStream_t stream) {
    const float* x_central = (const float*)d_in[0];
    const float* x_cont    = (const float*)d_in[1];
    const float* x_categ   = (const float*)d_in[2];
    const int* ei_c2cont   = (const int*)d_in[3];
    const int* ei_cont2c   = (const int*)d_in[4];
    const int* ei_c2categ  = (const int*)d_in[5];
    const int* ei_categ2c  = (const int*)d_in[6];
    const int* batch_central = (const int*)d_in[7];
    const int* batch_cont    = (const int*)d_in[8];
    const int* batch_categ   = (const int*)d_in[9];
    const float* Wp_central = (const float*)d_in[11];
    const float* bp_central = (const float*)d_in[12];
    const float* Wp_cont    = (const float*)d_in[13];
    const float* bp_cont    = (const float*)d_in[14];
    const float* Wp_categ   = (const float*)d_in[15];
    const float* bp_categ   = (const float*)d_in[16];
    const float* W_msg  = (const float*)d_in[17];
    const float* b_msg  = (const float*)d_in[18];
    const float* W_root = (const float*)d_in[19];
    const float* Wg     = (const float*)d_in[20];
    const float* bg     = (const float*)d_in[21];
    float* out = (float*)d_out;

    char* base = (char*)d_ws;
    size_t off = 0;
    auto alloc = [&](size_t bytes) -> void* {
        off = (off + 255) & ~(size_t)255;
        void* p = base + off; off += bytes; return p;
    };

    unsigned short* A0   = (unsigned short*)alloc((size_t)NCn * KA * 2);
    unsigned short* A1   = (unsigned short*)alloc((size_t)N1n * KA * 2);
    unsigned short* A2   = (unsigned short*)alloc((size_t)N2n * KA * 2);
    unsigned short* A0c  = (unsigned short*)alloc((size_t)NCn * 64 * 2);
    unsigned short* xr1c = (unsigned short*)alloc((size_t)N1n * 16 * 2);
    unsigned short* xr2c = (unsigned short*)alloc((size_t)N2n * 16 * 2);
    unsigned char* hc1   = (unsigned char*)alloc((size_t)NCn * 256);
    unsigned char* h11   = (unsigned char*)alloc((size_t)N1n * 256);
    unsigned char* h21   = (unsigned char*)alloc((size_t)N2n * 256);
    unsigned short* PG   = (unsigned short*)alloc((size_t)Bn * PGW * 2);
    float* emb           = (float*)alloc((size_t)Bn * Hh * 4);
    float* part          = (float*)alloc((size_t)28 * Bn * 256 * 4);   // 7 descs x 4 quarters

    unsigned short* Wt3  = (unsigned short*)alloc((size_t)3 * 256 * KA * 2);
    unsigned short* WPGt = (unsigned short*)alloc((size_t)256 * PGW * 2);
    float* bC  = (float*)alloc(256 * 4);
    float* bB1 = (float*)alloc(256 * 4);
    float* bB2 = (float*)alloc(256 * 4);
    float* bPG = (float*)alloc(256 * 4);

    const int ndst[4] = { N1n, NCn, N2n, NCn };
    int* rp[4]; uint2* pay[4];
    for (int r = 0; r < 4; ++r) {
        rp[r]  = (int*)alloc((size_t)(ndst[r] + 1) * 4);
        pay[r] = (uint2*)alloc((size_t)En * 8);
    }
    int* deg_fill = (int*)alloc((size_t)320000 * 4);   // [0,160000) deg, [160000,320000) fill
    int* partials = (int*)alloc(256 * 4);
    int* bounds   = (int*)alloc((size_t)3 * (Bn + 1) * 4);
    (void)ws_size; (void)in_sizes; (void)n_in; (void)out_size;

    const float* Wm0 = W_msg;
    const float* Wr0 = W_root;
    const float* Wm1 = W_msg  + (size_t)4 * 65536;
    const float* Wr1 = W_root + (size_t)4 * 65536;
    const float* bm0 = b_msg;
    const float* bm1 = b_msg + 4 * 256;

    // --- fused prep (pack + compact tables + zero + bounds) + weight prep ---
    prep_all<<<6257, 256, 0, stream>>>(x_central, x_cont, x_categ, A0, A1, A2,
                                       A0c, xr1c, xr2c, deg_fill,
                                       batch_central, batch_cont, batch_categ, bounds);
    wfold<<<dim3(256, 3), 128, 0, stream>>>(Wm0, Wr0, Wp_central, Wp_cont, Wp_categ, Wt3);
    wprep2<<<1794, 256, 0, stream>>>(Wm1, Wr1, bm1, Wm0, Wr0, bm0,
                                     bp_central, bp_cont, bp_categ,
                                     WPGt, bPG, bC, bB1, bB2);

    // --- CSR build (dst side) ---
    CPtr4 srcs = {{ ei_c2cont, ei_cont2c, ei_c2categ, ei_categ2c }};
    CPtr4 dsts = {{ ei_c2cont + En, ei_cont2c + En, ei_c2categ + En, ei_categ2c + En }};
    IPtr4 rps  = {{ rp[0], rp[1], rp[2], rp[3] }};
    CPtr4 rpc  = {{ rp[0], rp[1], rp[2], rp[3] }};
    UPtr4 pys  = {{ pay[0], pay[1], pay[2], pay[3] }};
    deg_count_all<<<3125, 256, 0, stream>>>(dsts, deg_fill);
    scan_chunk_all<<<158, 1024, 0, stream>>>(deg_fill, rps, partials);
    scan_partials_all<<<4, 64, 0, stream>>>(partials);
    scan_add_all<<<158, 1024, 0, stream>>>(rps, partials);
    scatter_all<<<3125, 256, 0, stream>>>(srcs, dsts, rpc, deg_fill + 160000, pys);

    // --- layer-0 raw aggregations (compact L2-resident gather sources) ---
    RawDesc r0 = { xr1c, rp[1], pay[1], A0, 16, 2, NCn, 64 };
    RawDesc r1 = { xr2c, rp[3], pay[3], A0, 16, 2, NCn, 80 };
    RawDesc r2 = { A0c,  rp[0], pay[0], A1, 64, 4, N1n, 0 };
    RawDesc r3 = { A0c,  rp[2], pay[2], A2, 64, 4, N2n, 0 };
    raw_agg<<<dim3(3750, 4), 256, 0, stream>>>(r0, r1, r2, r3);

    // --- layer-0 GEMMs (K=96, bias+relu, fp8 out) ---
    G96 gc = { A0, Wt3,                 bC,  hc1, NCn };
    G96 g1 = { A1, Wt3 + 1 * 256 * KA,  bB1, h11, N1n };
    G96 g2 = { A2, Wt3 + 2 * 256 * KA,  bB2, h21, N2n };
    gemm96<<<dim3(1875, 3), 256, 0, stream>>>(g1, g2, gc);

    // --- layer-1 collapsed: per-graph aggregation (7 descs x 4 quarters, fp8 gathers) ---
    PAll pa;
    pa.d[0] = { h11, bounds,                rp[1], pay[1] };       // -> ocol 0
    pa.d[1] = { h21, bounds,                rp[3], pay[3] };       // -> ocol 256
    pa.d[2] = { hc1, bounds,                nullptr, nullptr };    // -> 512
    pa.d[3] = { hc1, bounds + (Bn + 1),     rp[0], pay[0] };       // -> 768
    pa.d[4] = { h11, bounds + (Bn + 1),     nullptr, nullptr };    // -> 1024
    pa.d[5] = { hc1, bounds + 2 * (Bn + 1), rp[2], pay[2] };       // -> 1280
    pa.d[6] = { h21, bounds + 2 * (Bn + 1), nullptr, nullptr };    // -> 1536
    pg_all<<<dim3(Bn, 7, 4), 256, 0, stream>>>(pa, part);
    pg_combine<<<dim3(Bn, 7), 256, 0, stream>>>(part, bounds, PG);

    // --- final ---
    gemm_emb<<<Bn / 32, 256, 0, stream>>>(PG, WPGt, bPG, emb);
    out_final<<<Bn, 128, 0, stream>>>(emb, Wg, bg, out);
}

// Round 10
// 265.732 us; speedup vs baseline: 1.2911x; 1.2911x over previous
//
#include <hip/hip_runtime.h>

#define Hh   256
#define NCn  20000
#define N1n  60000
#define N2n  60000
#define En   200000
#define Bn   512
#define OUTn 128
#define KA   96        // layer-0 packed-A stride / GEMM K
#define PGW  1792      // per-graph concat width (7 x 256)

using bf16x8 = __attribute__((ext_vector_type(8))) __bf16;
using f32x4  = __attribute__((ext_vector_type(4))) float;
using f32x2  = __attribute__((ext_vector_type(2))) float;

__device__ __forceinline__ float bf2f(unsigned short u) {
    union { unsigned int i; float f; } v; v.i = ((unsigned int)u) << 16; return v.f;
}
__device__ __forceinline__ unsigned short f2bf(float f) {
    union { float f; unsigned int i; } v; v.f = f;
    unsigned int r = v.i + 0x7FFFu + ((v.i >> 16) & 1u);
    return (unsigned short)(r >> 16);
}
__device__ __forceinline__ int imax(int a, int b) { return a > b ? a : b; }

// ---- fp8 e4m3 pack/unpack (hardware cvt on gfx950; guarded manual fallback) -----------
#if __has_builtin(__builtin_amdgcn_cvt_pk_fp8_f32) && __has_builtin(__builtin_amdgcn_cvt_pk_f32_fp8)
__device__ __forceinline__ unsigned int pack4_fp8(float v0, float v1, float v2, float v3) {
    int r = __builtin_amdgcn_cvt_pk_fp8_f32(v0, v1, 0, false);
    r = __builtin_amdgcn_cvt_pk_fp8_f32(v2, v3, r, true);
    return (unsigned int)r;
}
__device__ __forceinline__ void unpack4_fp8(unsigned int u, float& v0, float& v1, float& v2, float& v3) {
    f32x2 lo = __builtin_amdgcn_cvt_pk_f32_fp8((int)u, false);
    f32x2 hi = __builtin_amdgcn_cvt_pk_f32_fp8((int)u, true);
    v0 = lo[0]; v1 = lo[1]; v2 = hi[0]; v3 = hi[1];
}
#else
__device__ __forceinline__ unsigned char f32_to_fp8_1(float f) {
    union { float f; unsigned int i; } v; v.f = f;
    unsigned int s = (v.i >> 24) & 0x80u;
    float af = fabsf(f);
    if (!(af > 0.f)) return (unsigned char)s;
    if (af > 448.f) af = 448.f;
    v.f = af;
    int e = (int)((v.i >> 23) & 0xff) - 127;
    unsigned int m = v.i & 0x7fffffu;
    if (e < -9) return (unsigned char)s;
    if (e < -6) {
        int rb = 21 + (-6 - e) - 1;
        unsigned int man = 0x800000u | m;
        unsigned int keep = man >> (rb + 1);
        unsigned int rem = man & ((1u << (rb + 1)) - 1);
        unsigned int half = 1u << rb;
        keep += (rem > half) || (rem == half && (keep & 1));
        return (unsigned char)(s | keep);
    }
    unsigned int keep = m >> 20;
    unsigned int rem = m & 0xfffffu;
    keep += (rem > 0x80000u) || (rem == 0x80000u && (keep & 1));
    unsigned int ee = (unsigned int)(e + 7);
    if (keep == 8) { keep = 0; ee += 1; }
    if (ee >= 16) { ee = 15; keep = 6; }
    return (unsigned char)(s | (ee << 3) | keep);
}
__device__ __forceinline__ unsigned int pack4_fp8(float v0, float v1, float v2, float v3) {
    return (unsigned int)f32_to_fp8_1(v0) | ((unsigned int)f32_to_fp8_1(v1) << 8) |
           ((unsigned int)f32_to_fp8_1(v2) << 16) | ((unsigned int)f32_to_fp8_1(v3) << 24);
}
__device__ __forceinline__ float fp8_to_f32_1(unsigned int b) {
    unsigned int s = b >> 7, e = (b >> 3) & 15u, m = b & 7u;
    float v;
    if (e == 0) v = (float)m * (1.0f / 512.0f);
    else { union { unsigned int i; float f; } u; u.i = ((e + 120u) << 23) | (m << 20); v = u.f; }
    return s ? -v : v;
}
__device__ __forceinline__ void unpack4_fp8(unsigned int u, float& v0, float& v1, float& v2, float& v3) {
    v0 = fp8_to_f32_1(u & 0xffu); v1 = fp8_to_f32_1((u >> 8) & 0xffu);
    v2 = fp8_to_f32_1((u >> 16) & 0xffu); v3 = fp8_to_f32_1((u >> 24) & 0xffu);
}
#endif

struct CPtr4 { const int* p[4]; };
struct IPtr4 { int* p[4]; };
struct UPtr4 { uint2* p[4]; };

// layer-1 per-graph stacked weight value WPG[k][n] (x 1/3)
__device__ __forceinline__ float wpg_val(const float* Wm1, const float* Wr1, int k, int n) {
    int blk = k >> 8, kk = k & 255;
    float v;
    switch (blk) {
        case 0:  v = 0.5f * Wm1[1 * 65536 + kk * 256 + n]; break;
        case 1:  v = 0.5f * Wm1[3 * 65536 + kk * 256 + n]; break;
        case 2:  v = 0.5f * (Wr1[1 * 65536 + kk * 256 + n] + Wr1[3 * 65536 + kk * 256 + n]); break;
        case 3:  v = Wm1[0 * 65536 + kk * 256 + n]; break;
        case 4:  v = Wr1[0 * 65536 + kk * 256 + n]; break;
        case 5:  v = Wm1[2 * 65536 + kk * 256 + n]; break;
        default: v = Wr1[2 * 65536 + kk * 256 + n]; break;
    }
    return v * (1.0f / 3.0f);
}

// ---------------- mega prep: pack + compact + zero + bounds + all weight folding -------
// block ranges: [0,B0) pack/zero/bounds; [B0,B1) Wt3 fold; [B1,B2) W2t; [B2] bias_fold; [B2+1] b2
#define PB0 6257
#define PB1 (PB0 + 384)
#define PB2 (PB1 + 896)
__global__ void __launch_bounds__(256) prep_mega(
        const float* __restrict__ xc, const float* __restrict__ x1, const float* __restrict__ x2,
        unsigned short* __restrict__ A0, unsigned short* __restrict__ A1,
        unsigned short* __restrict__ A2, unsigned short* __restrict__ A0c,
        unsigned short* __restrict__ xr1c, unsigned short* __restrict__ xr2c,
        int* __restrict__ deg_fill,
        const int* __restrict__ bc, const int* __restrict__ b1, const int* __restrict__ b2batch,
        int* __restrict__ bound,
        const float* __restrict__ Wm0, const float* __restrict__ Wr0,
        const float* __restrict__ bm0, const float* __restrict__ bpc,
        const float* __restrict__ bp1, const float* __restrict__ bp2,
        const float* __restrict__ Wpc, const float* __restrict__ Wp1, const float* __restrict__ Wp2,
        const float* __restrict__ Wm1, const float* __restrict__ Wr1,
        const float* __restrict__ bm1, const float* __restrict__ Wg, const float* __restrict__ bg,
        unsigned short* __restrict__ Wt3, unsigned short* __restrict__ W2t,
        float* __restrict__ bC, float* __restrict__ bB1, float* __restrict__ bB2,
        float* __restrict__ b2out) {
    __shared__ float smem[1536];
    const int b = blockIdx.x, t = threadIdx.x;
    if (b < PB0) {
        // ---- pack A panels + compact tables + zero deg_fill + graph bounds ----
        const int c0 = NCn * 16, c1 = c0 + N1n * 8, c2 = c1 + N2n * 8;
        const int c3 = c2 + 320000, c4 = c3 + 3 * (Bn + 1);
        int idx = b * 256 + t;
        if (idx < c0) {
            int m = idx >> 4, c = (idx & 15) * 4;
            float4 v = *reinterpret_cast<const float4*>(xc + (size_t)m * 64 + c);
            ushort4 o = { f2bf(v.x), f2bf(v.y), f2bf(v.z), f2bf(v.w) };
            *reinterpret_cast<ushort4*>(A0 + (size_t)m * KA + c) = o;
            *reinterpret_cast<ushort4*>(A0c + (size_t)m * 64 + c) = o;
        } else if (idx < c2) {
            bool is1 = idx < c1;
            int i = idx - (is1 ? c0 : c1);
            int m = i >> 3, c = (i & 7) * 4;
            const float* x = is1 ? x1 : x2;
            unsigned short* A = is1 ? A1 : A2;
            unsigned short* xr = is1 ? xr1c : xr2c;
            ushort4 o = { 0, 0, 0, 0 };
            if (c < 16) {
                float4 v = *reinterpret_cast<const float4*>(x + (size_t)m * 16 + c);
                o.x = f2bf(v.x); o.y = f2bf(v.y); o.z = f2bf(v.z); o.w = f2bf(v.w);
                *reinterpret_cast<ushort4*>(xr + (size_t)m * 16 + c) = o;
            }
            *reinterpret_cast<ushort4*>(A + (size_t)m * KA + 64 + c) = o;
        } else if (idx < c3) {
            deg_fill[idx - c2] = 0;
        } else if (idx < c4) {
            int i4 = idx - c3;
            int ty = i4 / (Bn + 1); int bb = i4 - ty * (Bn + 1);
            const int* batch = (ty == 0) ? bc : (ty == 1) ? b1 : b2batch;
            int n = (ty == 0) ? NCn : (ty == 1) ? N1n : N2n;
            int lo = 0, hi = n;
            while (lo < hi) { int mid = (lo + hi) >> 1; if (batch[mid] < bb) lo = mid + 1; else hi = mid; }
            bound[i4] = lo;
        }
    } else if (b < PB1) {
        // ---- layer-0 weight fold: Wt3 (2 n-cols per block) ----
        int b1i = b - PB0;
        int mat = b1i / 128, np = b1i % 128;
        int sub = t >> 7, tt = t & 127;
        int n = np * 2 + sub;
        float* cA = smem;            // [2][256]
        float* cB = smem + 512;
        float* cC = smem + 1024;
        for (int j = tt; j < 256; j += 128) {
            if (mat == 0) {
                cA[sub * 256 + j] = 0.5f * (Wr0[1 * 65536 + j * 256 + n] + Wr0[3 * 65536 + j * 256 + n]);
                cB[sub * 256 + j] = 0.5f * Wm0[1 * 65536 + j * 256 + n];
                cC[sub * 256 + j] = 0.5f * Wm0[3 * 65536 + j * 256 + n];
            } else if (mat == 1) {
                cA[sub * 256 + j] = Wm0[0 * 65536 + j * 256 + n];
                cB[sub * 256 + j] = Wr0[0 * 65536 + j * 256 + n];
                cC[sub * 256 + j] = 0.f;
            } else {
                cA[sub * 256 + j] = Wm0[2 * 65536 + j * 256 + n];
                cB[sub * 256 + j] = Wr0[2 * 65536 + j * 256 + n];
                cC[sub * 256 + j] = 0.f;
            }
        }
        __syncthreads();
        int k = tt;
        if (k < KA) {
            float w = 0.f;
            if (k < 64) {
                for (int j = 0; j < 256; ++j) w = fmaf(Wpc[k * 256 + j], cA[sub * 256 + j], w);
            } else if (k < 80) {
                const float* Wp = (mat == 2) ? Wp2 : Wp1;
                for (int j = 0; j < 256; ++j) w = fmaf(Wp[(k - 64) * 256 + j], cB[sub * 256 + j], w);
            } else if (mat == 0) {
                for (int j = 0; j < 256; ++j) w = fmaf(Wp2[(k - 80) * 256 + j], cC[sub * 256 + j], w);
            }
            Wt3[(size_t)mat * 256 * KA + n * KA + k] = f2bf(w);
        }
    } else if (b < PB2) {
        // ---- W2t[o][k] = sum_n WPG[k][n] * Wg[n][o], 2 k per block ----
        int kb = b - PB1;
        int k0 = kb * 2, k1 = k0 + 1;
        float* v0 = smem;           // [256]
        float* v1 = smem + 256;
        v0[t] = wpg_val(Wm1, Wr1, k0, t);
        v1[t] = wpg_val(Wm1, Wr1, k1, t);
        __syncthreads();
        int o = t & 127;
        const float* vv = (t < 128) ? v0 : v1;
        int kk = (t < 128) ? k0 : k1;
        float acc = 0.f;
        for (int n = 0; n < 256; ++n) acc = fmaf(vv[n], Wg[n * OUTn + o], acc);
        W2t[(size_t)o * PGW + kk] = f2bf(acc);
    } else if (b == PB2) {
        // ---- layer-0 folded biases ----
        int n = t;
        float s0 = 0, s1 = 0, s2 = 0, t0 = 0, t1 = 0, u0 = 0, u1 = 0;
        for (int j = 0; j < 256; ++j) {
            float wr1 = Wr0[1 * 65536 + j * 256 + n], wr3 = Wr0[3 * 65536 + j * 256 + n];
            float wm1 = Wm0[1 * 65536 + j * 256 + n], wm3 = Wm0[3 * 65536 + j * 256 + n];
            float wm0v = Wm0[0 * 65536 + j * 256 + n], wr0v = Wr0[0 * 65536 + j * 256 + n];
            float wm2 = Wm0[2 * 65536 + j * 256 + n], wr2 = Wr0[2 * 65536 + j * 256 + n];
            float bcv = bpc[j], b1v = bp1[j], b2v = bp2[j];
            s0 = fmaf(bcv, 0.5f * (wr1 + wr3), s0);
            s1 = fmaf(b1v, 0.5f * wm1, s1);
            s2 = fmaf(b2v, 0.5f * wm3, s2);
            t0 = fmaf(bcv, wm0v, t0); t1 = fmaf(b1v, wr0v, t1);
            u0 = fmaf(bcv, wm2, u0); u1 = fmaf(b2v, wr2, u1);
        }
        bC[n]  = s0 + s1 + s2 + 0.5f * (bm0[1 * 256 + n] + bm0[3 * 256 + n]);
        bB1[n] = t0 + t1 + bm0[0 * 256 + n];
        bB2[n] = u0 + u1 + bm0[2 * 256 + n];
    } else {
        // ---- b2[o] = sum_n bPG[n] * Wg[n][o] + bg[o] ----
        const float third = 1.0f / 3.0f;
        smem[t] = third * (0.5f * (bm1[1 * 256 + t] + bm1[3 * 256 + t]) +
                           bm1[0 * 256 + t] + bm1[2 * 256 + t]);
        __syncthreads();
        if (t < OUTn) {
            float acc = bg[t];
            for (int n = 0; n < 256; ++n) acc = fmaf(smem[n], Wg[n * OUTn + t], acc);
            b2out[t] = acc;
        }
    }
}

// ---------------- CSR build (relation-batched, dst side only) --------------------------
__device__ __forceinline__ int degoff_of(int rel) {
    const int t[4] = { 0, N1n, N1n + NCn, N1n + NCn + N2n };
    return t[rel];
}
__device__ __forceinline__ int nrel_of(int rel) {
    const int t[4] = { N1n, NCn, N2n, NCn };
    return t[rel];
}
__device__ __forceinline__ void rel_chunk(int b, int& rel, int& c) {
    if (b < 59)       { rel = 0; c = b; }
    else if (b < 79)  { rel = 1; c = b - 59; }
    else if (b < 138) { rel = 2; c = b - 79; }
    else              { rel = 3; c = b - 138; }
}
__global__ void deg_count_all(CPtr4 dst, int* __restrict__ deg_all) {
    int i = blockIdx.x * 256 + threadIdx.x;
    if (i >= 4 * En) return;
    int rel = i / En; int e = i - rel * En;
    atomicAdd(&deg_all[degoff_of(rel) + dst.p[rel][e]], 1);
}
__global__ void __launch_bounds__(1024) scan_chunk_all(const int* __restrict__ deg_all,
                                                       IPtr4 rp, int* __restrict__ partials) {
    int rel, c; rel_chunk(blockIdx.x, rel, c);
    int n = nrel_of(rel);
    __shared__ int sh[1024];
    int tid = threadIdx.x;
    int i = c * 1024 + tid;
    int v = (i < n) ? deg_all[degoff_of(rel) + i] : 0;
    sh[tid] = v; __syncthreads();
    for (int off = 1; off < 1024; off <<= 1) {
        int t = (tid >= off) ? sh[tid - off] : 0; __syncthreads();
        sh[tid] += t; __syncthreads();
    }
    if (i < n) rp.p[rel][i] = sh[tid] - v;
    if (tid == 1023) partials[rel * 64 + c] = sh[1023];
}
__global__ void scan_partials_all(int* partials) {
    const int nch[4] = { 59, 20, 59, 20 };
    int rel = blockIdx.x;
    __shared__ int sh[64];
    int tid = threadIdx.x;
    int v = (tid < nch[rel]) ? partials[rel * 64 + tid] : 0;
    sh[tid] = v; __syncthreads();
    for (int off = 1; off < 64; off <<= 1) {
        int t = (tid >= off) ? sh[tid - off] : 0; __syncthreads();
        sh[tid] += t; __syncthreads();
    }
    if (tid < nch[rel]) partials[rel * 64 + tid] = sh[tid] - v;
}
__global__ void __launch_bounds__(1024) scan_add_all(IPtr4 rp, const int* __restrict__ partials) {
    int rel, c; rel_chunk(blockIdx.x, rel, c);
    int n = nrel_of(rel);
    int tid = threadIdx.x;
    int i = c * 1024 + tid;
    if (i < n) rp.p[rel][i] += partials[rel * 64 + c];
    if (c == 0 && tid == 0) rp.p[rel][n] = En;
}
// scatter: pay[pos] = { src, 1/deg(dst) } in dst-CSR order
__global__ void scatter_all(CPtr4 src, CPtr4 dst, CPtr4 rp, int* fill_all, UPtr4 pay) {
    int i = blockIdx.x * 256 + threadIdx.x;
    if (i >= 4 * En) return;
    int rel = i / En; int e = i - rel * En;
    int d = dst.p[rel][e];
    int rb = rp.p[rel][d];
    int deg = rp.p[rel][d + 1] - rb;
    float w = 1.0f / (float)imax(deg, 1);
    int pos = rb + atomicAdd(&fill_all[degoff_of(rel) + d], 1);
    pay.p[rel][pos] = make_uint2((unsigned int)src.p[rel][e], __float_as_uint(w));
}

// ---------------- raw-feature segment mean (layer 0), compact L2-resident sources ------
struct RawDesc {
    const unsigned short* feat;   // compact table
    const int* rowptr;
    const uint2* pay;             // .x = src
    unsigned short* out;          // stride 96
    int fstride;                  // 16 or 64
    int sh;                       // log2(col-groups of 4)
    int n_dst;
    int ocol;
};
__global__ void raw_agg(RawDesc d0, RawDesc d1, RawDesc d2, RawDesc d3) {
    RawDesc d = (blockIdx.y == 0) ? d0 : (blockIdx.y == 1) ? d1 : (blockIdx.y == 2) ? d2 : d3;
    int idx = blockIdx.x * 256 + threadIdx.x;
    int node = idx >> d.sh;
    int c4 = idx & ((1 << d.sh) - 1);
    if (node >= d.n_dst) return;
    int s = d.rowptr[node], e = d.rowptr[node + 1];
    float a0 = 0.f, a1 = 0.f, a2 = 0.f, a3 = 0.f;
    float b0 = 0.f, b1 = 0.f, b2 = 0.f, b3 = 0.f;
    int i = s;
    for (; i + 1 < e; i += 2) {
        int sc1 = (int)d.pay[i].x, sc2 = (int)d.pay[i + 1].x;
        ushort4 v1 = *reinterpret_cast<const ushort4*>(d.feat + (size_t)sc1 * d.fstride + c4 * 4);
        ushort4 v2 = *reinterpret_cast<const ushort4*>(d.feat + (size_t)sc2 * d.fstride + c4 * 4);
        a0 += bf2f(v1.x); a1 += bf2f(v1.y); a2 += bf2f(v1.z); a3 += bf2f(v1.w);
        b0 += bf2f(v2.x); b1 += bf2f(v2.y); b2 += bf2f(v2.z); b3 += bf2f(v2.w);
    }
    if (i < e) {
        int sc1 = (int)d.pay[i].x;
        ushort4 v1 = *reinterpret_cast<const ushort4*>(d.feat + (size_t)sc1 * d.fstride + c4 * 4);
        a0 += bf2f(v1.x); a1 += bf2f(v1.y); a2 += bf2f(v1.z); a3 += bf2f(v1.w);
    }
    a0 += b0; a1 += b1; a2 += b2; a3 += b3;
    float inv = 1.0f / (float)imax(e - s, 1);
    ushort4 o;
    o.x = f2bf(a0 * inv); o.y = f2bf(a1 * inv); o.z = f2bf(a2 * inv); o.w = f2bf(a3 * inv);
    *reinterpret_cast<ushort4*>(d.out + (size_t)node * KA + d.ocol + c4 * 4) = o;
}

// ---------------- layer-0 GEMM: K=96, N=256, bias+relu, fp8 output ---------------------
struct G96 {
    const unsigned short* A;
    const unsigned short* Wt;
    const float* bias;
    unsigned char* C;          // fp8 e4m3, stride 256 B
    int M;
};
__global__ void __launch_bounds__(256) gemm96(G96 g0, G96 g1, G96 g2) {
    G96 g = (blockIdx.y == 0) ? g0 : (blockIdx.y == 1) ? g1 : g2;
    const int m0 = blockIdx.x * 32;
    if (m0 >= g.M) return;
    const int tid = threadIdx.x;
    const int wid = tid >> 6, lane = tid & 63;
    const int llo = lane & 15, lhi = lane >> 4;
    const int cb = wid * 64;

    const unsigned short* pA[2];
#pragma unroll
    for (int rt = 0; rt < 2; ++rt)
        pA[rt] = g.A + (size_t)(m0 + rt * 16 + llo) * KA + lhi * 8;
    const unsigned short* pB[4];
#pragma unroll
    for (int ct = 0; ct < 4; ++ct)
        pB[ct] = g.Wt + (size_t)(cb + ct * 16 + llo) * KA + lhi * 8;

    f32x4 acc[2][4] = {};
    bf16x8 a0[2], a1[2], a2[2], b0[4], b1[4], b2[4];
#pragma unroll
    for (int t = 0; t < 2; ++t) {
        a0[t] = *reinterpret_cast<const bf16x8*>(pA[t]);
        a1[t] = *reinterpret_cast<const bf16x8*>(pA[t] + 32);
        a2[t] = *reinterpret_cast<const bf16x8*>(pA[t] + 64);
    }
#pragma unroll
    for (int t = 0; t < 4; ++t) {
        b0[t] = *reinterpret_cast<const bf16x8*>(pB[t]);
        b1[t] = *reinterpret_cast<const bf16x8*>(pB[t] + 32);
        b2[t] = *reinterpret_cast<const bf16x8*>(pB[t] + 64);
    }
#pragma unroll
    for (int rt = 0; rt < 2; ++rt)
#pragma unroll
        for (int ct = 0; ct < 4; ++ct) {
            acc[rt][ct] = __builtin_amdgcn_mfma_f32_16x16x32_bf16(b0[ct], a0[rt], acc[rt][ct], 0, 0, 0);
            acc[rt][ct] = __builtin_amdgcn_mfma_f32_16x16x32_bf16(b1[ct], a1[rt], acc[rt][ct], 0, 0, 0);
            acc[rt][ct] = __builtin_amdgcn_mfma_f32_16x16x32_bf16(b2[ct], a2[rt], acc[rt][ct], 0, 0, 0);
        }

#pragma unroll
    for (int rt = 0; rt < 2; ++rt) {
        const int row = m0 + rt * 16 + llo;
#pragma unroll
        for (int ct = 0; ct < 4; ++ct) {
            const int col0 = cb + ct * 16 + lhi * 4;
            float4 bv = *reinterpret_cast<const float4*>(g.bias + col0);
            float v0 = fmaxf(acc[rt][ct][0] + bv.x, 0.f);
            float v1 = fmaxf(acc[rt][ct][1] + bv.y, 0.f);
            float v2 = fmaxf(acc[rt][ct][2] + bv.z, 0.f);
            float v3 = fmaxf(acc[rt][ct][3] + bv.w, 0.f);
            unsigned int o = pack4_fp8(v0, v1, v2, v3);
            *reinterpret_cast<unsigned int*>(g.C + (size_t)row * 256 + col0) = o;
        }
    }
}

// ---------------- per-graph aggregation: 7 descs x 4 quarters, 8-way edge ILP ----------
struct PDesc {
    const unsigned char* feat;    // [*][256] fp8
    const int* bound;             // 513 entries (per dst node type)
    const int* rowptr;            // nullptr => plain mean over nodes
    const uint2* pay;             // {src, 1/deg} per edge in CSR order
};
struct PAll { PDesc d[7]; };
// part[(desc*4+z)*512*256 + g*256 + col] (f32)
__global__ void __launch_bounds__(256) pg_all(PAll all, float* __restrict__ part) {
    PDesc d = all.d[blockIdx.y];
    const int g = blockIdx.x, z = blockIdx.z;
    const int tid = threadIdx.x, wid = tid >> 6, lane = tid & 63;
    const int ns = d.bound[g], ne = d.bound[g + 1];
    float r0 = 0.f, r1 = 0.f, r2 = 0.f, r3 = 0.f;
    if (d.rowptr) {
        const int es = d.rowptr[ns], ee = d.rowptr[ne];
        const int len = ee - es;
        const int s = es + ((len * z) >> 2), e = es + ((len * (z + 1)) >> 2);
        float a[4][4] = {};
        for (int i = s + wid * 8; i < e; i += 32) {
            uint2 p[8]; float w[8];
#pragma unroll
            for (int j = 0; j < 8; ++j) {
                int ij = i + j;
                bool ok = ij < e;
                p[j] = d.pay[ok ? ij : (e - 1)];
                w[j] = ok ? __uint_as_float(p[j].y) : 0.f;
            }
            unsigned int u[8];
#pragma unroll
            for (int j = 0; j < 8; ++j)
                u[j] = *reinterpret_cast<const unsigned int*>(
                    d.feat + (size_t)p[j].x * 256 + lane * 4);
#pragma unroll
            for (int j = 0; j < 8; ++j) {
                float f0, f1, f2, f3;
                unpack4_fp8(u[j], f0, f1, f2, f3);
                int q = j & 3;
                a[q][0] = fmaf(f0, w[j], a[q][0]);
                a[q][1] = fmaf(f1, w[j], a[q][1]);
                a[q][2] = fmaf(f2, w[j], a[q][2]);
                a[q][3] = fmaf(f3, w[j], a[q][3]);
            }
        }
        r0 = (a[0][0] + a[1][0]) + (a[2][0] + a[3][0]);
        r1 = (a[0][1] + a[1][1]) + (a[2][1] + a[3][1]);
        r2 = (a[0][2] + a[1][2]) + (a[2][2] + a[3][2]);
        r3 = (a[0][3] + a[1][3]) + (a[2][3] + a[3][3]);
    } else {
        const int len = ne - ns;
        const int s = ns + ((len * z) >> 2), e = ns + ((len * (z + 1)) >> 2);
        float a[4][4] = {};
        for (int n = s + wid * 4; n < e; n += 16) {
            unsigned int u[4];
#pragma unroll
            for (int j = 0; j < 4; ++j) {
                int nj = n + j;
                bool ok = nj < e;
                u[j] = ok ? *reinterpret_cast<const unsigned int*>(
                                d.feat + (size_t)nj * 256 + lane * 4) : 0u;
            }
#pragma unroll
            for (int j = 0; j < 4; ++j) {
                float f0, f1, f2, f3;
                unpack4_fp8(u[j], f0, f1, f2, f3);
                a[j][0] += f0; a[j][1] += f1; a[j][2] += f2; a[j][3] += f3;
            }
        }
        r0 = (a[0][0] + a[1][0]) + (a[2][0] + a[3][0]);
        r1 = (a[0][1] + a[1][1]) + (a[2][1] + a[3][1]);
        r2 = (a[0][2] + a[1][2]) + (a[2][2] + a[3][2]);
        r3 = (a[0][3] + a[1][3]) + (a[2][3] + a[3][3]);
    }
    __shared__ float sh[4][256];
    sh[wid][lane * 4 + 0] = r0; sh[wid][lane * 4 + 1] = r1;
    sh[wid][lane * 4 + 2] = r2; sh[wid][lane * 4 + 3] = r3;
    __syncthreads();
    float r = (sh[0][tid] + sh[1][tid]) + (sh[2][tid] + sh[3][tid]);
    part[(size_t)((blockIdx.y * 4 + z) * Bn + g) * 256 + tid] = r;
}

// ---------------- final: combine quarters -> PG row (LDS) -> out = PG @ W2t + b2 -------
__global__ void __launch_bounds__(256) final_direct(const float* __restrict__ part,
                                                    const int* __restrict__ bounds,
                                                    const unsigned short* __restrict__ W2t,
                                                    const float* __restrict__ b2,
                                                    float* __restrict__ out) {
    __shared__ float pgrow[PGW];
    __shared__ float red[256];
    const int btab[7] = { 0, 0, 0, 1, 1, 2, 2 };
    int g = blockIdx.x, t = threadIdx.x;
#pragma unroll
    for (int dsc = 0; dsc < 7; ++dsc) {
        const int* bb = bounds + btab[dsc] * (Bn + 1);
        int cnt = bb[g + 1] - bb[g];
        float s = 0.f;
#pragma unroll
        for (int z = 0; z < 4; ++z)
            s += part[(size_t)((dsc * 4 + z) * Bn + g) * 256 + t];
        pgrow[dsc * 256 + t] = s * (1.0f / (float)imax(cnt, 1));
    }
    __syncthreads();
    int o = t & 127, h = t >> 7;
    const unsigned short* wrow = W2t + (size_t)o * PGW + h * (PGW / 2);
    const float* prow = pgrow + h * (PGW / 2);
    float acc = 0.f;
    for (int k = 0; k < PGW / 2; k += 8) {
        ushort4 wa = *reinterpret_cast<const ushort4*>(wrow + k);
        ushort4 wb = *reinterpret_cast<const ushort4*>(wrow + k + 4);
        acc = fmaf(prow[k + 0], bf2f(wa.x), acc);
        acc = fmaf(prow[k + 1], bf2f(wa.y), acc);
        acc = fmaf(prow[k + 2], bf2f(wa.z), acc);
        acc = fmaf(prow[k + 3], bf2f(wa.w), acc);
        acc = fmaf(prow[k + 4], bf2f(wb.x), acc);
        acc = fmaf(prow[k + 5], bf2f(wb.y), acc);
        acc = fmaf(prow[k + 6], bf2f(wb.z), acc);
        acc = fmaf(prow[k + 7], bf2f(wb.w), acc);
    }
    red[t] = acc;
    __syncthreads();
    if (t < OUTn) out[(size_t)g * OUTn + t] = red[t] + red[t + 128] + b2[t];
}

// ---------------- host orchestration ----------------------------------------------------
extern "C" void kernel_launch(void* const* d_in, const int* in_sizes, int n_in,
                              void* d_out, int out_size, void* d_ws, size_t ws_size,
                              hipStream_t stream) {
    const float* x_central = (const float*)d_in[0];
    const float* x_cont    = (const float*)d_in[1];
    const float* x_categ   = (const float*)d_in[2];
    const int* ei_c2cont   = (const int*)d_in[3];
    const int* ei_cont2c   = (const int*)d_in[4];
    const int* ei_c2categ  = (const int*)d_in[5];
    const int* ei_categ2c  = (const int*)d_in[6];
    const int* batch_central = (const int*)d_in[7];
    const int* batch_cont    = (const int*)d_in[8];
    const int* batch_categ   = (const int*)d_in[9];
    const float* Wp_central = (const float*)d_in[11];
    const float* bp_central = (const float*)d_in[12];
    const float* Wp_cont    = (const float*)d_in[13];
    const float* bp_cont    = (const float*)d_in[14];
    const float* Wp_categ   = (const float*)d_in[15];
    const float* bp_categ   = (const float*)d_in[16];
    const float* W_msg  = (const float*)d_in[17];
    const float* b_msg  = (const float*)d_in[18];
    const float* W_root = (const float*)d_in[19];
    const float* Wg     = (const float*)d_in[20];
    const float* bg     = (const float*)d_in[21];
    float* out = (float*)d_out;

    char* base = (char*)d_ws;
    size_t off = 0;
    auto alloc = [&](size_t bytes) -> void* {
        off = (off + 255) & ~(size_t)255;
        void* p = base + off; off += bytes; return p;
    };

    unsigned short* A0   = (unsigned short*)alloc((size_t)NCn * KA * 2);
    unsigned short* A1   = (unsigned short*)alloc((size_t)N1n * KA * 2);
    unsigned short* A2   = (unsigned short*)alloc((size_t)N2n * KA * 2);
    unsigned short* A0c  = (unsigned short*)alloc((size_t)NCn * 64 * 2);
    unsigned short* xr1c = (unsigned short*)alloc((size_t)N1n * 16 * 2);
    unsigned short* xr2c = (unsigned short*)alloc((size_t)N2n * 16 * 2);
    unsigned char* hc1   = (unsigned char*)alloc((size_t)NCn * 256);
    unsigned char* h11   = (unsigned char*)alloc((size_t)N1n * 256);
    unsigned char* h21   = (unsigned char*)alloc((size_t)N2n * 256);
    float* part          = (float*)alloc((size_t)28 * Bn * 256 * 4);

    unsigned short* Wt3  = (unsigned short*)alloc((size_t)3 * 256 * KA * 2);
    unsigned short* W2t  = (unsigned short*)alloc((size_t)OUTn * PGW * 2);
    float* bC  = (float*)alloc(256 * 4);
    float* bB1 = (float*)alloc(256 * 4);
    float* bB2 = (float*)alloc(256 * 4);
    float* b2  = (float*)alloc(OUTn * 4);

    const int ndst[4] = { N1n, NCn, N2n, NCn };
    int* rp[4]; uint2* pay[4];
    for (int r = 0; r < 4; ++r) {
        rp[r]  = (int*)alloc((size_t)(ndst[r] + 1) * 4);
        pay[r] = (uint2*)alloc((size_t)En * 8);
    }
    int* deg_fill = (int*)alloc((size_t)320000 * 4);
    int* partials = (int*)alloc(256 * 4);
    int* bounds   = (int*)alloc((size_t)3 * (Bn + 1) * 4);
    (void)ws_size; (void)in_sizes; (void)n_in; (void)out_size;

    const float* Wm0 = W_msg;
    const float* Wr0 = W_root;
    const float* Wm1 = W_msg  + (size_t)4 * 65536;
    const float* Wr1 = W_root + (size_t)4 * 65536;
    const float* bm0 = b_msg;
    const float* bm1 = b_msg + 4 * 256;

    // --- mega prep: pack + compact + zero + bounds + all weight folding (1 dispatch) ---
    prep_mega<<<PB2 + 2, 256, 0, stream>>>(
        x_central, x_cont, x_categ, A0, A1, A2, A0c, xr1c, xr2c, deg_fill,
        batch_central, batch_cont, batch_categ, bounds,
        Wm0, Wr0, bm0, bp_central, bp_cont, bp_categ,
        Wp_central, Wp_cont, Wp_categ,
        Wm1, Wr1, bm1, Wg, bg,
        Wt3, W2t, bC, bB1, bB2, b2);

    // --- CSR build (dst side) ---
    CPtr4 srcs = {{ ei_c2cont, ei_cont2c, ei_c2categ, ei_categ2c }};
    CPtr4 dsts = {{ ei_c2cont + En, ei_cont2c + En, ei_c2categ + En, ei_categ2c + En }};
    IPtr4 rps  = {{ rp[0], rp[1], rp[2], rp[3] }};
    CPtr4 rpc  = {{ rp[0], rp[1], rp[2], rp[3] }};
    UPtr4 pys  = {{ pay[0], pay[1], pay[2], pay[3] }};
    deg_count_all<<<3125, 256, 0, stream>>>(dsts, deg_fill);
    scan_chunk_all<<<158, 1024, 0, stream>>>(deg_fill, rps, partials);
    scan_partials_all<<<4, 64, 0, stream>>>(partials);
    scan_add_all<<<158, 1024, 0, stream>>>(rps, partials);
    scatter_all<<<3125, 256, 0, stream>>>(srcs, dsts, rpc, deg_fill + 160000, pys);

    // --- layer-0 raw aggregations (compact L2-resident gather sources) ---
    RawDesc r0 = { xr1c, rp[1], pay[1], A0, 16, 2, NCn, 64 };
    RawDesc r1 = { xr2c, rp[3], pay[3], A0, 16, 2, NCn, 80 };
    RawDesc r2 = { A0c,  rp[0], pay[0], A1, 64, 4, N1n, 0 };
    RawDesc r3 = { A0c,  rp[2], pay[2], A2, 64, 4, N2n, 0 };
    raw_agg<<<dim3(3750, 4), 256, 0, stream>>>(r0, r1, r2, r3);

    // --- layer-0 GEMMs (K=96, bias+relu, fp8 out) ---
    G96 gc = { A0, Wt3,                 bC,  hc1, NCn };
    G96 g1 = { A1, Wt3 + 1 * 256 * KA,  bB1, h11, N1n };
    G96 g2 = { A2, Wt3 + 2 * 256 * KA,  bB2, h21, N2n };
    gemm96<<<dim3(1875, 3), 256, 0, stream>>>(g1, g2, gc);

    // --- layer-1 collapsed: per-graph aggregation (7 descs x 4 quarters, fp8 gathers) ---
    PAll pa;
    pa.d[0] = { h11, bounds,                rp[1], pay[1] };       // -> k-block 0
    pa.d[1] = { h21, bounds,                rp[3], pay[3] };       // -> 1
    pa.d[2] = { hc1, bounds,                nullptr, nullptr };    // -> 2
    pa.d[3] = { hc1, bounds + (Bn + 1),     rp[0], pay[0] };       // -> 3
    pa.d[4] = { h11, bounds + (Bn + 1),     nullptr, nullptr };    // -> 4
    pa.d[5] = { hc1, bounds + 2 * (Bn + 1), rp[2], pay[2] };       // -> 5
    pa.d[6] = { h21, bounds + 2 * (Bn + 1), nullptr, nullptr };    // -> 6
    pg_all<<<dim3(Bn, 7, 4), 256, 0, stream>>>(pa, part);

    // --- final: combine + PG @ W2 + b2 (1 dispatch) ---
    final_direct<<<Bn, 256, 0, stream>>>(part, bounds, W2t, b2, out);
}

// Round 11
// 247.073 us; speedup vs baseline: 1.3886x; 1.0755x over previous
//
#include <hip/hip_runtime.h>

#define Hh   256
#define NCn  20000
#define N1n  60000
#define N2n  60000
#define En   200000
#define Bn   512
#define OUTn 128
#define KA   96        // layer-0 packed-A stride / GEMM K
#define PGW  1792      // per-graph concat width (7 x 256)

using bf16x8 = __attribute__((ext_vector_type(8))) __bf16;
using f32x4  = __attribute__((ext_vector_type(4))) float;
using f32x2  = __attribute__((ext_vector_type(2))) float;

__device__ __forceinline__ float bf2f(unsigned short u) {
    union { unsigned int i; float f; } v; v.i = ((unsigned int)u) << 16; return v.f;
}
__device__ __forceinline__ unsigned short f2bf(float f) {
    union { float f; unsigned int i; } v; v.f = f;
    unsigned int r = v.i + 0x7FFFu + ((v.i >> 16) & 1u);
    return (unsigned short)(r >> 16);
}
__device__ __forceinline__ int imax(int a, int b) { return a > b ? a : b; }

// ---- fp8 e4m3 pack/unpack (hardware cvt on gfx950; guarded manual fallback) -----------
#if __has_builtin(__builtin_amdgcn_cvt_pk_fp8_f32) && __has_builtin(__builtin_amdgcn_cvt_pk_f32_fp8)
__device__ __forceinline__ unsigned int pack4_fp8(float v0, float v1, float v2, float v3) {
    int r = __builtin_amdgcn_cvt_pk_fp8_f32(v0, v1, 0, false);
    r = __builtin_amdgcn_cvt_pk_fp8_f32(v2, v3, r, true);
    return (unsigned int)r;
}
__device__ __forceinline__ void unpack4_fp8(unsigned int u, float& v0, float& v1, float& v2, float& v3) {
    f32x2 lo = __builtin_amdgcn_cvt_pk_f32_fp8((int)u, false);
    f32x2 hi = __builtin_amdgcn_cvt_pk_f32_fp8((int)u, true);
    v0 = lo[0]; v1 = lo[1]; v2 = hi[0]; v3 = hi[1];
}
#else
__device__ __forceinline__ unsigned char f32_to_fp8_1(float f) {
    union { float f; unsigned int i; } v; v.f = f;
    unsigned int s = (v.i >> 24) & 0x80u;
    float af = fabsf(f);
    if (!(af > 0.f)) return (unsigned char)s;
    if (af > 448.f) af = 448.f;
    v.f = af;
    int e = (int)((v.i >> 23) & 0xff) - 127;
    unsigned int m = v.i & 0x7fffffu;
    if (e < -9) return (unsigned char)s;
    if (e < -6) {
        int rb = 21 + (-6 - e) - 1;
        unsigned int man = 0x800000u | m;
        unsigned int keep = man >> (rb + 1);
        unsigned int rem = man & ((1u << (rb + 1)) - 1);
        unsigned int half = 1u << rb;
        keep += (rem > half) || (rem == half && (keep & 1));
        return (unsigned char)(s | keep);
    }
    unsigned int keep = m >> 20;
    unsigned int rem = m & 0xfffffu;
    keep += (rem > 0x80000u) || (rem == 0x80000u && (keep & 1));
    unsigned int ee = (unsigned int)(e + 7);
    if (keep == 8) { keep = 0; ee += 1; }
    if (ee >= 16) { ee = 15; keep = 6; }
    return (unsigned char)(s | (ee << 3) | keep);
}
__device__ __forceinline__ unsigned int pack4_fp8(float v0, float v1, float v2, float v3) {
    return (unsigned int)f32_to_fp8_1(v0) | ((unsigned int)f32_to_fp8_1(v1) << 8) |
           ((unsigned int)f32_to_fp8_1(v2) << 16) | ((unsigned int)f32_to_fp8_1(v3) << 24);
}
__device__ __forceinline__ float fp8_to_f32_1(unsigned int b) {
    unsigned int s = b >> 7, e = (b >> 3) & 15u, m = b & 7u;
    float v;
    if (e == 0) v = (float)m * (1.0f / 512.0f);
    else { union { unsigned int i; float f; } u; u.i = ((e + 120u) << 23) | (m << 20); v = u.f; }
    return s ? -v : v;
}
__device__ __forceinline__ void unpack4_fp8(unsigned int u, float& v0, float& v1, float& v2, float& v3) {
    v0 = fp8_to_f32_1(u & 0xffu); v1 = fp8_to_f32_1((u >> 8) & 0xffu);
    v2 = fp8_to_f32_1((u >> 16) & 0xffu); v3 = fp8_to_f32_1((u >> 24) & 0xffu);
}
#endif

struct CPtr4 { const int* p[4]; };
struct IPtr4 { int* p[4]; };
struct UPtr4 { uint2* p[4]; };

// layer-1 per-graph stacked weight value WPG[k][n] (x 1/3)
__device__ __forceinline__ float wpg_val(const float* Wm1, const float* Wr1, int k, int n) {
    int blk = k >> 8, kk = k & 255;
    float v;
    switch (blk) {
        case 0:  v = 0.5f * Wm1[1 * 65536 + kk * 256 + n]; break;
        case 1:  v = 0.5f * Wm1[3 * 65536 + kk * 256 + n]; break;
        case 2:  v = 0.5f * (Wr1[1 * 65536 + kk * 256 + n] + Wr1[3 * 65536 + kk * 256 + n]); break;
        case 3:  v = Wm1[0 * 65536 + kk * 256 + n]; break;
        case 4:  v = Wr1[0 * 65536 + kk * 256 + n]; break;
        case 5:  v = Wm1[2 * 65536 + kk * 256 + n]; break;
        default: v = Wr1[2 * 65536 + kk * 256 + n]; break;
    }
    return v * (1.0f / 3.0f);
}

// ---------------- mega prep -------------------------------------------------------------
// block ranges: [0,QB0) pack/zero/bounds; [QB0,QB1) Wt3 fold (coalesced, block=(mat,k));
// [QB1,QB2) W2t; [QB2,QB3) bias folds (3 blocks); [QB3] b2
#define QB0 6257
#define QB1 (QB0 + 288)
#define QB2 (QB1 + 896)
#define QB3 (QB2 + 3)
__global__ void __launch_bounds__(256) prep_mega(
        const float* __restrict__ xc, const float* __restrict__ x1, const float* __restrict__ x2,
        unsigned short* __restrict__ A0, unsigned short* __restrict__ A1,
        unsigned short* __restrict__ A2, unsigned short* __restrict__ A0c,
        unsigned short* __restrict__ xr1c, unsigned short* __restrict__ xr2c,
        int* __restrict__ deg_fill,
        const int* __restrict__ bc, const int* __restrict__ b1, const int* __restrict__ b2batch,
        int* __restrict__ bound,
        const float* __restrict__ Wm0, const float* __restrict__ Wr0,
        const float* __restrict__ bm0, const float* __restrict__ bpc,
        const float* __restrict__ bp1, const float* __restrict__ bp2,
        const float* __restrict__ Wpc, const float* __restrict__ Wp1, const float* __restrict__ Wp2,
        const float* __restrict__ Wm1, const float* __restrict__ Wr1,
        const float* __restrict__ bm1, const float* __restrict__ Wg, const float* __restrict__ bg,
        unsigned short* __restrict__ Wt3, unsigned short* __restrict__ W2t,
        float* __restrict__ bC, float* __restrict__ bB1, float* __restrict__ bB2,
        float* __restrict__ b2out) {
    __shared__ float smem[512];
    const int b = blockIdx.x, t = threadIdx.x;
    if (b < QB0) {
        // ---- pack A panels + compact tables + zero deg_fill + graph bounds ----
        const int c0 = NCn * 16, c1 = c0 + N1n * 8, c2 = c1 + N2n * 8;
        const int c3 = c2 + 320000, c4 = c3 + 3 * (Bn + 1);
        int idx = b * 256 + t;
        if (idx < c0) {
            int m = idx >> 4, c = (idx & 15) * 4;
            float4 v = *reinterpret_cast<const float4*>(xc + (size_t)m * 64 + c);
            ushort4 o = { f2bf(v.x), f2bf(v.y), f2bf(v.z), f2bf(v.w) };
            *reinterpret_cast<ushort4*>(A0 + (size_t)m * KA + c) = o;
            *reinterpret_cast<ushort4*>(A0c + (size_t)m * 64 + c) = o;
        } else if (idx < c2) {
            bool is1 = idx < c1;
            int i = idx - (is1 ? c0 : c1);
            int m = i >> 3, c = (i & 7) * 4;
            const float* x = is1 ? x1 : x2;
            unsigned short* A = is1 ? A1 : A2;
            unsigned short* xr = is1 ? xr1c : xr2c;
            ushort4 o = { 0, 0, 0, 0 };
            if (c < 16) {
                float4 v = *reinterpret_cast<const float4*>(x + (size_t)m * 16 + c);
                o.x = f2bf(v.x); o.y = f2bf(v.y); o.z = f2bf(v.z); o.w = f2bf(v.w);
                *reinterpret_cast<ushort4*>(xr + (size_t)m * 16 + c) = o;
            }
            *reinterpret_cast<ushort4*>(A + (size_t)m * KA + 64 + c) = o;
        } else if (idx < c3) {
            deg_fill[idx - c2] = 0;
        } else if (idx < c4) {
            int i4 = idx - c3;
            int ty = i4 / (Bn + 1); int bb = i4 - ty * (Bn + 1);
            const int* batch = (ty == 0) ? bc : (ty == 1) ? b1 : b2batch;
            int n = (ty == 0) ? NCn : (ty == 1) ? N1n : N2n;
            int lo = 0, hi = n;
            while (lo < hi) { int mid = (lo + hi) >> 1; if (batch[mid] < bb) lo = mid + 1; else hi = mid; }
            bound[i4] = lo;
        }
    } else if (b < QB1) {
        // ---- Wt3 fold v2: block=(mat,k), threads=n; coalesced W reads, scalar Wp reads ----
        int bi = b - QB0;
        int mat = bi / 96, k = bi - mat * 96;
        int n = t;
        float acc = 0.f;
        if (k < 64) {
            const float* wp = Wpc + k * 256;
            if (mat == 0) {
#pragma unroll 8
                for (int j = 0; j < 256; ++j)
                    acc = fmaf(wp[j], 0.5f * (Wr0[1 * 65536 + j * 256 + n] + Wr0[3 * 65536 + j * 256 + n]), acc);
            } else if (mat == 1) {
#pragma unroll 8
                for (int j = 0; j < 256; ++j)
                    acc = fmaf(wp[j], Wm0[0 * 65536 + j * 256 + n], acc);
            } else {
#pragma unroll 8
                for (int j = 0; j < 256; ++j)
                    acc = fmaf(wp[j], Wm0[2 * 65536 + j * 256 + n], acc);
            }
        } else if (k < 80) {
            int kk = k - 64;
            if (mat == 0) {
                const float* wp = Wp1 + kk * 256;
#pragma unroll 8
                for (int j = 0; j < 256; ++j)
                    acc = fmaf(wp[j], 0.5f * Wm0[1 * 65536 + j * 256 + n], acc);
            } else if (mat == 1) {
                const float* wp = Wp1 + kk * 256;
#pragma unroll 8
                for (int j = 0; j < 256; ++j)
                    acc = fmaf(wp[j], Wr0[0 * 65536 + j * 256 + n], acc);
            } else {
                const float* wp = Wp2 + kk * 256;
#pragma unroll 8
                for (int j = 0; j < 256; ++j)
                    acc = fmaf(wp[j], Wr0[2 * 65536 + j * 256 + n], acc);
            }
        } else {
            if (mat == 0) {
                const float* wp = Wp2 + (k - 80) * 256;
#pragma unroll 8
                for (int j = 0; j < 256; ++j)
                    acc = fmaf(wp[j], 0.5f * Wm0[3 * 65536 + j * 256 + n], acc);
            }
            // mat 1/2: zero pad
        }
        Wt3[(size_t)mat * 256 * KA + n * KA + k] = f2bf(acc);
    } else if (b < QB2) {
        // ---- W2t[o][k] = sum_n WPG[k][n] * Wg[n][o], 2 k per block ----
        int kb = b - QB1;
        int k0 = kb * 2, k1 = k0 + 1;
        float* v0 = smem;           // [256]
        float* v1 = smem + 256;
        v0[t] = wpg_val(Wm1, Wr1, k0, t);
        v1[t] = wpg_val(Wm1, Wr1, k1, t);
        __syncthreads();
        int o = t & 127;
        const float* vv = (t < 128) ? v0 : v1;
        int kk = (t < 128) ? k0 : k1;
        float acc = 0.f;
        for (int n = 0; n < 256; ++n) acc = fmaf(vv[n], Wg[n * OUTn + o], acc);
        W2t[(size_t)o * PGW + kk] = f2bf(acc);
    } else if (b < QB3) {
        // ---- layer-0 folded biases: one block per output vector ----
        int which = b - QB2;
        int n = t;
        if (which == 0) {
            float s0 = 0, s1 = 0, s2 = 0;
#pragma unroll 4
            for (int j = 0; j < 256; ++j) {
                float wr1 = Wr0[1 * 65536 + j * 256 + n], wr3 = Wr0[3 * 65536 + j * 256 + n];
                float wm1 = Wm0[1 * 65536 + j * 256 + n], wm3 = Wm0[3 * 65536 + j * 256 + n];
                s0 = fmaf(bpc[j], 0.5f * (wr1 + wr3), s0);
                s1 = fmaf(bp1[j], 0.5f * wm1, s1);
                s2 = fmaf(bp2[j], 0.5f * wm3, s2);
            }
            bC[n] = s0 + s1 + s2 + 0.5f * (bm0[1 * 256 + n] + bm0[3 * 256 + n]);
        } else if (which == 1) {
            float t0 = 0, t1 = 0;
#pragma unroll 4
            for (int j = 0; j < 256; ++j) {
                t0 = fmaf(bpc[j], Wm0[0 * 65536 + j * 256 + n], t0);
                t1 = fmaf(bp1[j], Wr0[0 * 65536 + j * 256 + n], t1);
            }
            bB1[n] = t0 + t1 + bm0[0 * 256 + n];
        } else {
            float u0 = 0, u1 = 0;
#pragma unroll 4
            for (int j = 0; j < 256; ++j) {
                u0 = fmaf(bpc[j], Wm0[2 * 65536 + j * 256 + n], u0);
                u1 = fmaf(bp2[j], Wr0[2 * 65536 + j * 256 + n], u1);
            }
            bB2[n] = u0 + u1 + bm0[2 * 256 + n];
        }
    } else {
        // ---- b2[o] = sum_n bPG[n] * Wg[n][o] + bg[o] ----
        const float third = 1.0f / 3.0f;
        smem[t] = third * (0.5f * (bm1[1 * 256 + t] + bm1[3 * 256 + t]) +
                           bm1[0 * 256 + t] + bm1[2 * 256 + t]);
        __syncthreads();
        if (t < OUTn) {
            float acc = bg[t];
            for (int n = 0; n < 256; ++n) acc = fmaf(smem[n], Wg[n * OUTn + t], acc);
            b2out[t] = acc;
        }
    }
}

// ---------------- CSR build (relation-batched, dst side only) --------------------------
__device__ __forceinline__ int degoff_of(int rel) {
    const int t[4] = { 0, N1n, N1n + NCn, N1n + NCn + N2n };
    return t[rel];
}
__device__ __forceinline__ int nrel_of(int rel) {
    const int t[4] = { N1n, NCn, N2n, NCn };
    return t[rel];
}
__device__ __forceinline__ void rel_chunk(int b, int& rel, int& c) {
    if (b < 59)       { rel = 0; c = b; }
    else if (b < 79)  { rel = 1; c = b - 59; }
    else if (b < 138) { rel = 2; c = b - 79; }
    else              { rel = 3; c = b - 138; }
}
__global__ void deg_count_all(CPtr4 dst, int* __restrict__ deg_all) {
    int i = blockIdx.x * 256 + threadIdx.x;
    if (i >= 4 * En) return;
    int rel = i / En; int e = i - rel * En;
    atomicAdd(&deg_all[degoff_of(rel) + dst.p[rel][e]], 1);
}
__global__ void __launch_bounds__(1024) scan_chunk_all(const int* __restrict__ deg_all,
                                                       IPtr4 rp, int* __restrict__ partials) {
    int rel, c; rel_chunk(blockIdx.x, rel, c);
    int n = nrel_of(rel);
    __shared__ int sh[1024];
    int tid = threadIdx.x;
    int i = c * 1024 + tid;
    int v = (i < n) ? deg_all[degoff_of(rel) + i] : 0;
    sh[tid] = v; __syncthreads();
    for (int off = 1; off < 1024; off <<= 1) {
        int t = (tid >= off) ? sh[tid - off] : 0; __syncthreads();
        sh[tid] += t; __syncthreads();
    }
    if (i < n) rp.p[rel][i] = sh[tid] - v;
    if (tid == 1023) partials[rel * 64 + c] = sh[1023];
}
__global__ void scan_partials_all(int* partials) {
    const int nch[4] = { 59, 20, 59, 20 };
    int rel = blockIdx.x;
    __shared__ int sh[64];
    int tid = threadIdx.x;
    int v = (tid < nch[rel]) ? partials[rel * 64 + tid] : 0;
    sh[tid] = v; __syncthreads();
    for (int off = 1; off < 64; off <<= 1) {
        int t = (tid >= off) ? sh[tid - off] : 0; __syncthreads();
        sh[tid] += t; __syncthreads();
    }
    if (tid < nch[rel]) partials[rel * 64 + tid] = sh[tid] - v;
}
__global__ void __launch_bounds__(1024) scan_add_all(IPtr4 rp, const int* __restrict__ partials) {
    int rel, c; rel_chunk(blockIdx.x, rel, c);
    int n = nrel_of(rel);
    int tid = threadIdx.x;
    int i = c * 1024 + tid;
    if (i < n) rp.p[rel][i] += partials[rel * 64 + c];
    if (c == 0 && tid == 0) rp.p[rel][n] = En;
}
// scatter: pay[pos] = { src, 1/deg(dst) } in dst-CSR order
__global__ void scatter_all(CPtr4 src, CPtr4 dst, CPtr4 rp, int* fill_all, UPtr4 pay) {
    int i = blockIdx.x * 256 + threadIdx.x;
    if (i >= 4 * En) return;
    int rel = i / En; int e = i - rel * En;
    int d = dst.p[rel][e];
    int rb = rp.p[rel][d];
    int deg = rp.p[rel][d + 1] - rb;
    float w = 1.0f / (float)imax(deg, 1);
    int pos = rb + atomicAdd(&fill_all[degoff_of(rel) + d], 1);
    pay.p[rel][pos] = make_uint2((unsigned int)src.p[rel][e], __float_as_uint(w));
}

// ---------------- raw-feature segment mean (layer 0), compact L2-resident sources ------
struct RawDesc {
    const unsigned short* feat;   // compact table
    const int* rowptr;
    const uint2* pay;             // .x = src
    unsigned short* out;          // stride 96
    int fstride;                  // 16 or 64
    int sh;                       // log2(col-groups of 4)
    int n_dst;
    int ocol;
};
__global__ void raw_agg(RawDesc d0, RawDesc d1, RawDesc d2, RawDesc d3) {
    RawDesc d = (blockIdx.y == 0) ? d0 : (blockIdx.y == 1) ? d1 : (blockIdx.y == 2) ? d2 : d3;
    int idx = blockIdx.x * 256 + threadIdx.x;
    int node = idx >> d.sh;
    int c4 = idx & ((1 << d.sh) - 1);
    if (node >= d.n_dst) return;
    int s = d.rowptr[node], e = d.rowptr[node + 1];
    float a0 = 0.f, a1 = 0.f, a2 = 0.f, a3 = 0.f;
    float b0 = 0.f, b1 = 0.f, b2 = 0.f, b3 = 0.f;
    int i = s;
    for (; i + 1 < e; i += 2) {
        int sc1 = (int)d.pay[i].x, sc2 = (int)d.pay[i + 1].x;
        ushort4 v1 = *reinterpret_cast<const ushort4*>(d.feat + (size_t)sc1 * d.fstride + c4 * 4);
        ushort4 v2 = *reinterpret_cast<const ushort4*>(d.feat + (size_t)sc2 * d.fstride + c4 * 4);
        a0 += bf2f(v1.x); a1 += bf2f(v1.y); a2 += bf2f(v1.z); a3 += bf2f(v1.w);
        b0 += bf2f(v2.x); b1 += bf2f(v2.y); b2 += bf2f(v2.z); b3 += bf2f(v2.w);
    }
    if (i < e) {
        int sc1 = (int)d.pay[i].x;
        ushort4 v1 = *reinterpret_cast<const ushort4*>(d.feat + (size_t)sc1 * d.fstride + c4 * 4);
        a0 += bf2f(v1.x); a1 += bf2f(v1.y); a2 += bf2f(v1.z); a3 += bf2f(v1.w);
    }
    a0 += b0; a1 += b1; a2 += b2; a3 += b3;
    float inv = 1.0f / (float)imax(e - s, 1);
    ushort4 o;
    o.x = f2bf(a0 * inv); o.y = f2bf(a1 * inv); o.z = f2bf(a2 * inv); o.w = f2bf(a3 * inv);
    *reinterpret_cast<ushort4*>(d.out + (size_t)node * KA + d.ocol + c4 * 4) = o;
}

// ---------------- layer-0 GEMM: K=96, N=256, bias+relu, fp8 output ---------------------
struct G96 {
    const unsigned short* A;
    const unsigned short* Wt;
    const float* bias;
    unsigned char* C;          // fp8 e4m3, stride 256 B
    int M;
};
__global__ void __launch_bounds__(256) gemm96(G96 g0, G96 g1, G96 g2) {
    G96 g = (blockIdx.y == 0) ? g0 : (blockIdx.y == 1) ? g1 : g2;
    const int m0 = blockIdx.x * 32;
    if (m0 >= g.M) return;
    const int tid = threadIdx.x;
    const int wid = tid >> 6, lane = tid & 63;
    const int llo = lane & 15, lhi = lane >> 4;
    const int cb = wid * 64;

    const unsigned short* pA[2];
#pragma unroll
    for (int rt = 0; rt < 2; ++rt)
        pA[rt] = g.A + (size_t)(m0 + rt * 16 + llo) * KA + lhi * 8;
    const unsigned short* pB[4];
#pragma unroll
    for (int ct = 0; ct < 4; ++ct)
        pB[ct] = g.Wt + (size_t)(cb + ct * 16 + llo) * KA + lhi * 8;

    f32x4 acc[2][4] = {};
    bf16x8 a0[2], a1[2], a2[2], b0[4], b1[4], b2[4];
#pragma unroll
    for (int t = 0; t < 2; ++t) {
        a0[t] = *reinterpret_cast<const bf16x8*>(pA[t]);
        a1[t] = *reinterpret_cast<const bf16x8*>(pA[t] + 32);
        a2[t] = *reinterpret_cast<const bf16x8*>(pA[t] + 64);
    }
#pragma unroll
    for (int t = 0; t < 4; ++t) {
        b0[t] = *reinterpret_cast<const bf16x8*>(pB[t]);
        b1[t] = *reinterpret_cast<const bf16x8*>(pB[t] + 32);
        b2[t] = *reinterpret_cast<const bf16x8*>(pB[t] + 64);
    }
#pragma unroll
    for (int rt = 0; rt < 2; ++rt)
#pragma unroll
        for (int ct = 0; ct < 4; ++ct) {
            acc[rt][ct] = __builtin_amdgcn_mfma_f32_16x16x32_bf16(b0[ct], a0[rt], acc[rt][ct], 0, 0, 0);
            acc[rt][ct] = __builtin_amdgcn_mfma_f32_16x16x32_bf16(b1[ct], a1[rt], acc[rt][ct], 0, 0, 0);
            acc[rt][ct] = __builtin_amdgcn_mfma_f32_16x16x32_bf16(b2[ct], a2[rt], acc[rt][ct], 0, 0, 0);
        }

#pragma unroll
    for (int rt = 0; rt < 2; ++rt) {
        const int row = m0 + rt * 16 + llo;
#pragma unroll
        for (int ct = 0; ct < 4; ++ct) {
            const int col0 = cb + ct * 16 + lhi * 4;
            float4 bv = *reinterpret_cast<const float4*>(g.bias + col0);
            float v0 = fmaxf(acc[rt][ct][0] + bv.x, 0.f);
            float v1 = fmaxf(acc[rt][ct][1] + bv.y, 0.f);
            float v2 = fmaxf(acc[rt][ct][2] + bv.z, 0.f);
            float v3 = fmaxf(acc[rt][ct][3] + bv.w, 0.f);
            unsigned int o = pack4_fp8(v0, v1, v2, v3);
            *reinterpret_cast<unsigned int*>(g.C + (size_t)row * 256 + col0) = o;
        }
    }
}

// ---------------- per-graph aggregation: 7 descs x 4 quarters, 8-way edge ILP ----------
struct PDesc {
    const unsigned char* feat;    // [*][256] fp8
    const int* bound;             // 513 entries (per dst node type)
    const int* rowptr;            // nullptr => plain mean over nodes
    const uint2* pay;             // {src, 1/deg} per edge in CSR order
};
struct PAll { PDesc d[7]; };
// part[(desc*4+z)*512*256 + g*256 + col] (f32)
__global__ void __launch_bounds__(256) pg_all(PAll all, float* __restrict__ part) {
    PDesc d = all.d[blockIdx.y];
    const int g = blockIdx.x, z = blockIdx.z;
    const int tid = threadIdx.x, wid = tid >> 6, lane = tid & 63;
    const int ns = d.bound[g], ne = d.bound[g + 1];
    float r0 = 0.f, r1 = 0.f, r2 = 0.f, r3 = 0.f;
    if (d.rowptr) {
        const int es = d.rowptr[ns], ee = d.rowptr[ne];
        const int len = ee - es;
        const int s = es + ((len * z) >> 2), e = es + ((len * (z + 1)) >> 2);
        float a[4][4] = {};
        for (int i = s + wid * 8; i < e; i += 32) {
            uint2 p[8]; float w[8];
#pragma unroll
            for (int j = 0; j < 8; ++j) {
                int ij = i + j;
                bool ok = ij < e;
                p[j] = d.pay[ok ? ij : (e - 1)];
                w[j] = ok ? __uint_as_float(p[j].y) : 0.f;
            }
            unsigned int u[8];
#pragma unroll
            for (int j = 0; j < 8; ++j)
                u[j] = *reinterpret_cast<const unsigned int*>(
                    d.feat + (size_t)p[j].x * 256 + lane * 4);
#pragma unroll
            for (int j = 0; j < 8; ++j) {
                float f0, f1, f2, f3;
                unpack4_fp8(u[j], f0, f1, f2, f3);
                int q = j & 3;
                a[q][0] = fmaf(f0, w[j], a[q][0]);
                a[q][1] = fmaf(f1, w[j], a[q][1]);
                a[q][2] = fmaf(f2, w[j], a[q][2]);
                a[q][3] = fmaf(f3, w[j], a[q][3]);
            }
        }
        r0 = (a[0][0] + a[1][0]) + (a[2][0] + a[3][0]);
        r1 = (a[0][1] + a[1][1]) + (a[2][1] + a[3][1]);
        r2 = (a[0][2] + a[1][2]) + (a[2][2] + a[3][2]);
        r3 = (a[0][3] + a[1][3]) + (a[2][3] + a[3][3]);
    } else {
        const int len = ne - ns;
        const int s = ns + ((len * z) >> 2), e = ns + ((len * (z + 1)) >> 2);
        float a[4][4] = {};
        for (int n = s + wid * 4; n < e; n += 16) {
            unsigned int u[4];
#pragma unroll
            for (int j = 0; j < 4; ++j) {
                int nj = n + j;
                bool ok = nj < e;
                u[j] = ok ? *reinterpret_cast<const unsigned int*>(
                                d.feat + (size_t)nj * 256 + lane * 4) : 0u;
            }
#pragma unroll
            for (int j = 0; j < 4; ++j) {
                float f0, f1, f2, f3;
                unpack4_fp8(u[j], f0, f1, f2, f3);
                a[j][0] += f0; a[j][1] += f1; a[j][2] += f2; a[j][3] += f3;
            }
        }
        r0 = (a[0][0] + a[1][0]) + (a[2][0] + a[3][0]);
        r1 = (a[0][1] + a[1][1]) + (a[2][1] + a[3][1]);
        r2 = (a[0][2] + a[1][2]) + (a[2][2] + a[3][2]);
        r3 = (a[0][3] + a[1][3]) + (a[2][3] + a[3][3]);
    }
    __shared__ float sh[4][256];
    sh[wid][lane * 4 + 0] = r0; sh[wid][lane * 4 + 1] = r1;
    sh[wid][lane * 4 + 2] = r2; sh[wid][lane * 4 + 3] = r3;
    __syncthreads();
    float r = (sh[0][tid] + sh[1][tid]) + (sh[2][tid] + sh[3][tid]);
    part[(size_t)((blockIdx.y * 4 + z) * Bn + g) * 256 + tid] = r;
}

// ---------------- final: combine quarters -> PG row (LDS) -> out = PG @ W2t + b2 -------
__global__ void __launch_bounds__(256) final_direct(const float* __restrict__ part,
                                                    const int* __restrict__ bounds,
                                                    const unsigned short* __restrict__ W2t,
                                                    const float* __restrict__ b2,
                                                    float* __restrict__ out) {
    __shared__ float pgrow[PGW];
    __shared__ float red[256];
    const int btab[7] = { 0, 0, 0, 1, 1, 2, 2 };
    int g = blockIdx.x, t = threadIdx.x;
#pragma unroll
    for (int dsc = 0; dsc < 7; ++dsc) {
        const int* bb = bounds + btab[dsc] * (Bn + 1);
        int cnt = bb[g + 1] - bb[g];
        float s = 0.f;
#pragma unroll
        for (int z = 0; z < 4; ++z)
            s += part[(size_t)((dsc * 4 + z) * Bn + g) * 256 + t];
        pgrow[dsc * 256 + t] = s * (1.0f / (float)imax(cnt, 1));
    }
    __syncthreads();
    int o = t & 127, h = t >> 7;
    const unsigned short* wrow = W2t + (size_t)o * PGW + h * (PGW / 2);
    const float* prow = pgrow + h * (PGW / 2);
    float acc = 0.f;
    for (int k = 0; k < PGW / 2; k += 8) {
        ushort4 wa = *reinterpret_cast<const ushort4*>(wrow + k);
        ushort4 wb = *reinterpret_cast<const ushort4*>(wrow + k + 4);
        acc = fmaf(prow[k + 0], bf2f(wa.x), acc);
        acc = fmaf(prow[k + 1], bf2f(wa.y), acc);
        acc = fmaf(prow[k + 2], bf2f(wa.z), acc);
        acc = fmaf(prow[k + 3], bf2f(wa.w), acc);
        acc = fmaf(prow[k + 4], bf2f(wb.x), acc);
        acc = fmaf(prow[k + 5], bf2f(wb.y), acc);
        acc = fmaf(prow[k + 6], bf2f(wb.z), acc);
        acc = fmaf(prow[k + 7], bf2f(wb.w), acc);
    }
    red[t] = acc;
    __syncthreads();
    if (t < OUTn) out[(size_t)g * OUTn + t] = red[t] + red[t + 128] + b2[t];
}

// ---------------- host orchestration ----------------------------------------------------
extern "C" void kernel_launch(void* const* d_in, const int* in_sizes, int n_in,
                              void* d_out, int out_size, void* d_ws, size_t ws_size,
                              hipStream_t stream) {
    const float* x_central = (const float*)d_in[0];
    const float* x_cont    = (const float*)d_in[1];
    const float* x_categ   = (const float*)d_in[2];
    const int* ei_c2cont   = (const int*)d_in[3];
    const int* ei_cont2c   = (const int*)d_in[4];
    const int* ei_c2categ  = (const int*)d_in[5];
    const int* ei_categ2c  = (const int*)d_in[6];
    const int* batch_central = (const int*)d_in[7];
    const int* batch_cont    = (const int*)d_in[8];
    const int* batch_categ   = (const int*)d_in[9];
    const float* Wp_central = (const float*)d_in[11];
    const float* bp_central = (const float*)d_in[12];
    const float* Wp_cont    = (const float*)d_in[13];
    const float* bp_cont    = (const float*)d_in[14];
    const float* Wp_categ   = (const float*)d_in[15];
    const float* bp_categ   = (const float*)d_in[16];
    const float* W_msg  = (const float*)d_in[17];
    const float* b_msg  = (const float*)d_in[18];
    const float* W_root = (const float*)d_in[19];
    const float* Wg     = (const float*)d_in[20];
    const float* bg     = (const float*)d_in[21];
    float* out = (float*)d_out;

    char* base = (char*)d_ws;
    size_t off = 0;
    auto alloc = [&](size_t bytes) -> void* {
        off = (off + 255) & ~(size_t)255;
        void* p = base + off; off += bytes; return p;
    };

    unsigned short* A0   = (unsigned short*)alloc((size_t)NCn * KA * 2);
    unsigned short* A1   = (unsigned short*)alloc((size_t)N1n * KA * 2);
    unsigned short* A2   = (unsigned short*)alloc((size_t)N2n * KA * 2);
    unsigned short* A0c  = (unsigned short*)alloc((size_t)NCn * 64 * 2);
    unsigned short* xr1c = (unsigned short*)alloc((size_t)N1n * 16 * 2);
    unsigned short* xr2c = (unsigned short*)alloc((size_t)N2n * 16 * 2);
    unsigned char* hc1   = (unsigned char*)alloc((size_t)NCn * 256);
    unsigned char* h11   = (unsigned char*)alloc((size_t)N1n * 256);
    unsigned char* h21   = (unsigned char*)alloc((size_t)N2n * 256);
    float* part          = (float*)alloc((size_t)28 * Bn * 256 * 4);

    unsigned short* Wt3  = (unsigned short*)alloc((size_t)3 * 256 * KA * 2);
    unsigned short* W2t  = (unsigned short*)alloc((size_t)OUTn * PGW * 2);
    float* bC  = (float*)alloc(256 * 4);
    float* bB1 = (float*)alloc(256 * 4);
    float* bB2 = (float*)alloc(256 * 4);
    float* b2  = (float*)alloc(OUTn * 4);

    const int ndst[4] = { N1n, NCn, N2n, NCn };
    int* rp[4]; uint2* pay[4];
    for (int r = 0; r < 4; ++r) {
        rp[r]  = (int*)alloc((size_t)(ndst[r] + 1) * 4);
        pay[r] = (uint2*)alloc((size_t)En * 8);
    }
    int* deg_fill = (int*)alloc((size_t)320000 * 4);
    int* partials = (int*)alloc(256 * 4);
    int* bounds   = (int*)alloc((size_t)3 * (Bn + 1) * 4);
    (void)ws_size; (void)in_sizes; (void)n_in; (void)out_size;

    const float* Wm0 = W_msg;
    const float* Wr0 = W_root;
    const float* Wm1 = W_msg  + (size_t)4 * 65536;
    const float* Wr1 = W_root + (size_t)4 * 65536;
    const float* bm0 = b_msg;
    const float* bm1 = b_msg + 4 * 256;

    // --- mega prep (1 dispatch) ---
    prep_mega<<<QB3 + 1, 256, 0, stream>>>(
        x_central, x_cont, x_categ, A0, A1, A2, A0c, xr1c, xr2c, deg_fill,
        batch_central, batch_cont, batch_categ, bounds,
        Wm0, Wr0, bm0, bp_central, bp_cont, bp_categ,
        Wp_central, Wp_cont, Wp_categ,
        Wm1, Wr1, bm1, Wg, bg,
        Wt3, W2t, bC, bB1, bB2, b2);

    // --- CSR build (dst side) ---
    CPtr4 srcs = {{ ei_c2cont, ei_cont2c, ei_c2categ, ei_categ2c }};
    CPtr4 dsts = {{ ei_c2cont + En, ei_cont2c + En, ei_c2categ + En, ei_categ2c + En }};
    IPtr4 rps  = {{ rp[0], rp[1], rp[2], rp[3] }};
    CPtr4 rpc  = {{ rp[0], rp[1], rp[2], rp[3] }};
    UPtr4 pys  = {{ pay[0], pay[1], pay[2], pay[3] }};
    deg_count_all<<<3125, 256, 0, stream>>>(dsts, deg_fill);
    scan_chunk_all<<<158, 1024, 0, stream>>>(deg_fill, rps, partials);
    scan_partials_all<<<4, 64, 0, stream>>>(partials);
    scan_add_all<<<158, 1024, 0, stream>>>(rps, partials);
    scatter_all<<<3125, 256, 0, stream>>>(srcs, dsts, rpc, deg_fill + 160000, pys);

    // --- layer-0 raw aggregations (compact L2-resident gather sources) ---
    RawDesc r0 = { xr1c, rp[1], pay[1], A0, 16, 2, NCn, 64 };
    RawDesc r1 = { xr2c, rp[3], pay[3], A0, 16, 2, NCn, 80 };
    RawDesc r2 = { A0c,  rp[0], pay[0], A1, 64, 4, N1n, 0 };
    RawDesc r3 = { A0c,  rp[2], pay[2], A2, 64, 4, N2n, 0 };
    raw_agg<<<dim3(3750, 4), 256, 0, stream>>>(r0, r1, r2, r3);

    // --- layer-0 GEMMs (K=96, bias+relu, fp8 out) ---
    G96 gc = { A0, Wt3,                 bC,  hc1, NCn };
    G96 g1 = { A1, Wt3 + 1 * 256 * KA,  bB1, h11, N1n };
    G96 g2 = { A2, Wt3 + 2 * 256 * KA,  bB2, h21, N2n };
    gemm96<<<dim3(1875, 3), 256, 0, stream>>>(g1, g2, gc);

    // --- layer-1 collapsed: per-graph aggregation (7 descs x 4 quarters, fp8 gathers) ---
    PAll pa;
    pa.d[0] = { h11, bounds,                rp[1], pay[1] };
    pa.d[1] = { h21, bounds,                rp[3], pay[3] };
    pa.d[2] = { hc1, bounds,                nullptr, nullptr };
    pa.d[3] = { hc1, bounds + (Bn + 1),     rp[0], pay[0] };
    pa.d[4] = { h11, bounds + (Bn + 1),     nullptr, nullptr };
    pa.d[5] = { hc1, bounds + 2 * (Bn + 1), rp[2], pay[2] };
    pa.d[6] = { h21, bounds + 2 * (Bn + 1), nullptr, nullptr };
    pg_all<<<dim3(Bn, 7, 4), 256, 0, stream>>>(pa, part);

    // --- final: combine + PG @ W2 + b2 (1 dispatch) ---
    final_direct<<<Bn, 256, 0, stream>>>(part, bounds, W2t, b2, out);
}